// Round 8
// baseline (575.787 us; speedup 1.0000x reference)
//
#include <hip/hip_runtime.h>
#include <math.h>

// Problem constants
#define B_  16
#define L_  128
#define E_  34
#define A_  36
#define D_  300
#define H_  256
#define KP_ 320     // D padded to mult of 32 (bf16 MFMA K)
#define G4_ 1024    // 4*H
#define KC_ 512     // 2*H
#define NCAT_ 128   // padded 36(base)+36(trig)+34(evh)
#define WAS_ 1092   // Wa row stride = 4H + A-1 + E-1
#define WES_ 545    // We row stride = 2H + E-1

// Workspace layout (float offsets)
#define O_HX     1310720u   // u64[2][128][64] tagged h exchange (parity dbuf)
#define O_BSUM_F 1343488u   // [1024] bih+bhh
#define O_BSUM_B 1344512u
#define O_ZPRE   1345536u   // [2][128][16][1024]  x@WihT + bias, in processing order
#define O_HIDDEN 5539840u   // [128][16][512]  hs-layout (t,b), fwd [0:256), bwd [256:512)
#define O_WCAT   6588416u   // [512][128]  cols: 0..35 Wa_hidden, 36..71 Wa_trig, 72..105 We_hidden
#define O_BVEC   6653952u   // [128]       ba | 0 | be
#define O_P      6654080u   // [2048][128] hidden @ Wcat + bvec   (rows m = t*16+b)
#define O_EVTAG  6916224u   // int [16][128]  self-tagged event preds ((i+1)<<8 | p)
#define O_ZTAG   6918272u   // int [32]    zpre m-tile completion counters (dir*16+tile)

#define HIX(k) ((k) + (((k) >> 5) << 2))   // +4 float pad per 32 to stagger banks

// lgkm-only barrier: skips the vmcnt(0) store-ack/prefetch drain __syncthreads emits.
// Safe when the barrier only orders LDS traffic (global deps handled by data deps).
#define BARRIER_LGKM() asm volatile("s_waitcnt lgkmcnt(0)\n\ts_barrier" ::: "memory")

typedef short bf16x8 __attribute__((ext_vector_type(8)));
typedef float f32x4  __attribute__((ext_vector_type(4)));

__device__ __forceinline__ float fsig(float x) {
    return __builtin_amdgcn_rcpf(1.0f + __expf(-x));
}
__device__ __forceinline__ float ftanh(float x) {
    float e = __expf(-2.0f * fabsf(x));          // (0,1] - no overflow
    float t = (1.0f - e) * __builtin_amdgcn_rcpf(1.0f + e);
    return copysignf(t, x);
}
__device__ __forceinline__ unsigned short f2bf(float f) {   // RNE f32->bf16
    unsigned u = __float_as_uint(f);
    return (unsigned short)((u + 0x7fffu + ((u >> 16) & 1u)) >> 16);
}
__device__ __forceinline__ float bf2f(unsigned short h) {
    return __uint_as_float(((unsigned)h) << 16);
}

// ---------------------------------------------------------------- prep (tiny now)
// The X/Wih hi-lo staging moved into k_main's gemm role (in-register cast from the
// fp32 sources). Prep keeps bsum/Wcat/bvec and clears the zpre tile counters.
__global__ void k_prep(const float* __restrict__ bih_f, const float* __restrict__ bhh_f,
                       const float* __restrict__ bih_b, const float* __restrict__ bhh_b,
                       const float* __restrict__ We, const float* __restrict__ be,
                       const float* __restrict__ Wa, const float* __restrict__ ba,
                       float* __restrict__ ws) {
    const int N3 = 2 * 1024;     // bsum
    const int N4 = 65536;        // Wcat
    const int N5 = 128;          // bvec
    const int N6 = 32;           // ztag clear
    const int total = N3 + N4 + N5 + N6;
    for (int idx = blockIdx.x * blockDim.x + threadIdx.x; idx < total;
         idx += gridDim.x * blockDim.x) {
        int i = idx;
        if (i < N3) {
            int dir = i / 1024, r = i % 1024;
            ws[(dir ? O_BSUM_B : O_BSUM_F) + r] =
                (dir ? bih_b[r] + bhh_b[r] : bih_f[r] + bhh_f[r]);
            continue;
        }
        i -= N3;
        if (i < N4) {
            int k = i >> 7, n = i & 127;
            float v = 0.0f;
            if (n < 36)               v = Wa[n * WAS_ + k];
            else if (n < 72)          v = Wa[(n - 36) * WAS_ + KC_ + k];
            else if (n < 106)         v = We[(n - 72) * WES_ + k];
            ws[O_WCAT + i] = v;
            continue;
        }
        i -= N4;
        if (i < N5) {
            float v = 0.0f;
            if (i < 36)               v = ba[i];
            else if (i >= 72 && i < 106) v = be[i - 72];
            ws[O_BVEC + i] = v;
            continue;
        }
        i -= N5;
        __hip_atomic_store(&((int*)(ws + O_ZTAG))[i], 0,
                           __ATOMIC_RELAXED, __HIP_MEMORY_SCOPE_AGENT);
    }
}

// ------------------------------------------------- FUSED: gemm1-producer + LSTM-consumer
// Blocks 0..127: LSTM role (r7 protocol, verified). Blocks 128..383: GEMM role,
// one 128x128 zpre tile each (bf16x3 split precision, r5-verified math), casting
// fp32 emb/Wih to bf16 hi/lo IN-REGISTER while staging (kills k_prep's 10.5MB of
// intermediate traffic). Producer->consumer handoff via agent-scope (MALL) tile
// counters: each of the 8 n-blocks of a (dir,mtile) fetch_add(RELEASE)s the
// counter after vmcnt-drained agent stores of z; lstm polls counter==8 once per
// 8 steps (gemm runs ~16x faster than lstm consumes -> only tile 0 ever waits).
// z reads are relaxed agent u64 loads (MALL-coherent; prefetched a full step
// ahead so the ~900cy latency hides). Same proven sync class as hx64/evtag --
// NOT the r1-r3 L2-shortcut family.
// Deadlock-safe: lstm blocks (dispatched first) occupy <=128 CUs; >=128 CUs
// remain for gemm-role blocks, which have no dependencies.
__global__ __launch_bounds__(512) void k_main(const int* __restrict__ ids,
                                              const float* __restrict__ emb,
                                              const float* __restrict__ Wih_f,
                                              const float* __restrict__ Wih_b,
                                              const float* __restrict__ Whh_f,
                                              const float* __restrict__ Whh_b,
                                              float* __restrict__ ws) {
    __shared__ __align__(16) unsigned short smem[4 * 128 * 40];   // 40960 B, role-aliased
    int* ztag = (int*)(ws + O_ZTAG);
    int tid = threadIdx.x;

    if (blockIdx.x < 128) {
        // ================= LSTM role =================
        int phys = blockIdx.x;
        int g    = phys >> 5;
        int cb   = phys & 31;
        int b    = cb & 15;
        int dir  = cb >> 4;
        int rg   = tid >> 3;             // 0..63 -> 4 local gate rows each
        int kc   = tid & 7;              // 0..7  -> k chunk of 32

        const float* Whh  = dir ? Whh_b : Whh_f;
        const float* zpre = ws + O_ZPRE + (size_t)dir * 2048 * G4_;
        float* hid = ws + O_HIDDEN;
        unsigned long long* hx64 = (unsigned long long*)(ws + O_HX);

        float* h_sh = (float*)smem;                  // HIX(255)+5 = 288 floats
        float* zbuf = (float*)smem + 288;            // 256 floats

        int lr0  = rg << 2;
        int ggr0 = (lr0 >> 6) * 256 + g * 64 + (lr0 & 63);
        float4 w[4][8];
#pragma unroll
        for (int i = 0; i < 4; i++) {
            const float* wr = Whh + (size_t)(ggr0 + i) * H_ + (kc << 5);
#pragma unroll
            for (int c = 0; c < 8; c++) w[i][c] = *(const float4*)(wr + (c << 2));
        }
        for (int k = tid; k < 288; k += 512) h_sh[k] = 0.0f;
        float c_state = 0.0f;
        int cur_tile = -1;
        float4 zv = make_float4(0.f, 0.f, 0.f, 0.f);
        if (kc == 0) {
            // wait for zpre tile 0 (all 8 n-blocks), then load row for s=0
            int v, cnt = 0;
            do {
                v = __hip_atomic_load(&ztag[dir * 16], __ATOMIC_RELAXED,
                                      __HIP_MEMORY_SCOPE_AGENT);
                if (v < 8) __builtin_amdgcn_s_sleep(2);
            } while (v < 8 && ++cnt < (1 << 22));
            cur_tile = 0;
            const unsigned long long* zr =
                (const unsigned long long*)(zpre + (size_t)(0 * B_ + b) * G4_ + ggr0);
            unsigned long long z0 = __hip_atomic_load(zr, __ATOMIC_RELAXED,
                                                      __HIP_MEMORY_SCOPE_AGENT);
            unsigned long long z1 = __hip_atomic_load(zr + 1, __ATOMIC_RELAXED,
                                                      __HIP_MEMORY_SCOPE_AGENT);
            zv.x = __uint_as_float((unsigned)z0); zv.y = __uint_as_float((unsigned)(z0 >> 32));
            zv.z = __uint_as_float((unsigned)z1); zv.w = __uint_as_float((unsigned)(z1 >> 32));
        }
        __syncthreads();

        for (int s = 0; s < L_; s++) {
            float4 zn = make_float4(0.f, 0.f, 0.f, 0.f);
            if (kc == 0 && s + 1 < L_) {
                int nt = (s + 1) >> 3;
                if (nt != cur_tile) {
                    int v, cnt = 0;
                    do {
                        v = __hip_atomic_load(&ztag[dir * 16 + nt], __ATOMIC_RELAXED,
                                              __HIP_MEMORY_SCOPE_AGENT);
                        if (v < 8) __builtin_amdgcn_s_sleep(2);
                    } while (v < 8 && ++cnt < (1 << 22));
                    cur_tile = nt;
                }
                const unsigned long long* zr =
                    (const unsigned long long*)(zpre + (size_t)((s + 1) * B_ + b) * G4_ + ggr0);
                unsigned long long z0 = __hip_atomic_load(zr, __ATOMIC_RELAXED,
                                                          __HIP_MEMORY_SCOPE_AGENT);
                unsigned long long z1 = __hip_atomic_load(zr + 1, __ATOMIC_RELAXED,
                                                          __HIP_MEMORY_SCOPE_AGENT);
                zn.x = __uint_as_float((unsigned)z0); zn.y = __uint_as_float((unsigned)(z0 >> 32));
                zn.z = __uint_as_float((unsigned)z1); zn.w = __uint_as_float((unsigned)(z1 >> 32));
            }
            float a0 = 0.f, a1 = 0.f, a2 = 0.f, a3 = 0.f;
            const float* hp = &h_sh[kc * 36];
#pragma unroll
            for (int c = 0; c < 8; c++) {
                float4 hv = *(const float4*)(hp + (c << 2));
                a0 = fmaf(w[0][c].x, hv.x, a0); a0 = fmaf(w[0][c].y, hv.y, a0);
                a0 = fmaf(w[0][c].z, hv.z, a0); a0 = fmaf(w[0][c].w, hv.w, a0);
                a1 = fmaf(w[1][c].x, hv.x, a1); a1 = fmaf(w[1][c].y, hv.y, a1);
                a1 = fmaf(w[1][c].z, hv.z, a1); a1 = fmaf(w[1][c].w, hv.w, a1);
                a2 = fmaf(w[2][c].x, hv.x, a2); a2 = fmaf(w[2][c].y, hv.y, a2);
                a2 = fmaf(w[2][c].z, hv.z, a2); a2 = fmaf(w[2][c].w, hv.w, a2);
                a3 = fmaf(w[3][c].x, hv.x, a3); a3 = fmaf(w[3][c].y, hv.y, a3);
                a3 = fmaf(w[3][c].z, hv.z, a3); a3 = fmaf(w[3][c].w, hv.w, a3);
            }
#pragma unroll
            for (int m = 1; m < 8; m <<= 1) {
                a0 += __shfl_xor(a0, m); a1 += __shfl_xor(a1, m);
                a2 += __shfl_xor(a2, m); a3 += __shfl_xor(a3, m);
            }
            if (kc == 0) {
                float4 z4;
                z4.x = a0 + zv.x; z4.y = a1 + zv.y; z4.z = a2 + zv.z; z4.w = a3 + zv.w;
                *(float4*)&zbuf[lr0] = z4;
            }
            zv = zn;
            BARRIER_LGKM();
            int par = (s + 1) & 1;
            if (tid < 64) {
                float fi = fsig(zbuf[tid]);
                float ff = fsig(zbuf[tid + 64]);
                float gg = ftanh(zbuf[tid + 128]);
                float fo = fsig(zbuf[tid + 192]);
                c_state = ff * c_state + fi * gg;
                float h = fo * ftanh(c_state);
                int hr = g * 64 + tid;
                // publish FIRST: visibility latency is the critical path
                if (s + 1 < L_) {
                    unsigned long long pk =
                        ((unsigned long long)(unsigned)(s + 1) << 32) |
                        (unsigned)__float_as_uint(h);
                    __hip_atomic_store(&hx64[(par << 13) + (phys << 6) + tid], pk,
                                       __ATOMIC_RELAXED, __HIP_MEMORY_SCOPE_AGENT);
                }
                h_sh[HIX(hr)] = h;
                int t_orig = dir ? (L_ - 1 - s) : s;
                hid[(size_t)(t_orig * B_ + b) * KC_ + dir * H_ + hr] = h;
            }
            if (tid >= 64 && tid < 256 && s + 1 < L_) {
                int which = tid >> 6;                 // 1..3
                int sg = (g + which) & 3;
                int sb = cb | (sg << 5);              // sibling physical block id
                int u  = tid & 63;
                const unsigned long long* wp = &hx64[(par << 13) + (sb << 6) + u];
                unsigned long long v;
                int cnt = 0;
                // phase-align the first poll with publish visibility (r7: -12us)
                __builtin_amdgcn_s_sleep(6);
                do {
                    v = __hip_atomic_load(wp, __ATOMIC_RELAXED, __HIP_MEMORY_SCOPE_AGENT);
                } while ((int)(v >> 32) < s + 1 && ++cnt < (1 << 20));
                h_sh[HIX(sg * 64 + u)] = __uint_as_float((unsigned)v);
            }
            BARRIER_LGKM();
        }
    } else {
        // ================= GEMM role (one 128x128 zpre tile) =================
        int gid = blockIdx.x - 128;
        int dir = gid >> 7;
        int rem = gid & 127;
        int mtile = rem >> 3;
        int m0 = mtile << 7;
        int n0 = (rem & 7) << 7;
        const float* Wih = dir ? Wih_b : Wih_f;
        const float* bsv = ws + (dir ? O_BSUM_B : O_BSUM_F);

        unsigned short* Ah = smem;
        unsigned short* Al = smem + 5120;
        unsigned short* Bh = smem + 10240;
        unsigned short* Bl = smem + 15360;

        int w = tid >> 6, lane = tid & 63;
        int wr = w >> 2, wc = w & 3;               // 2x4 waves of 64m x 32n
        int lr = lane & 15, lk = lane >> 4;

        int sr = tid >> 2, sh = tid & 3;            // stage: row sr, 8 elems at col sh*8
        int gm = m0 + sr;
        int tt = gm >> 4, bb2 = gm & 15;
        int t_orig = dir ? (L_ - 1 - tt) : tt;
        int aid = ids[bb2 * L_ + t_orig];
        const float* arow = emb + (size_t)aid * D_;
        const float* brow = Wih + (size_t)(n0 + sr) * D_;
        int swb = sr * 80 + sh * 16;

        f32x4 acc[4][2] = {};
        for (int k0 = 0; k0 < KP_; k0 += 32) {
            int cb0 = k0 + sh * 8;
            bf16x8 vah, val, vbh, vbl;
#pragma unroll
            for (int e = 0; e < 8; e++) {
                int c = cb0 + e;
                float fa = (c < D_) ? arow[c] : 0.0f;
                float fb = (c < D_) ? brow[c] : 0.0f;
                unsigned short ha = f2bf(fa);
                unsigned short hb = f2bf(fb);
                vah[e] = (short)ha; val[e] = (short)f2bf(fa - bf2f(ha));
                vbh[e] = (short)hb; vbl[e] = (short)f2bf(fb - bf2f(hb));
            }
            *(bf16x8*)((char*)Ah + swb) = vah;
            *(bf16x8*)((char*)Al + swb) = val;
            *(bf16x8*)((char*)Bh + swb) = vbh;
            *(bf16x8*)((char*)Bl + swb) = vbl;
            __syncthreads();
            bf16x8 afh[4], afl[4], bfh[2], bfl[2];
#pragma unroll
            for (int mi = 0; mi < 4; mi++) {
                int rb = (wr * 64 + mi * 16 + lr) * 80 + lk * 16;
                afh[mi] = *(const bf16x8*)((const char*)Ah + rb);
                afl[mi] = *(const bf16x8*)((const char*)Al + rb);
            }
#pragma unroll
            for (int ni = 0; ni < 2; ni++) {
                int rb = (wc * 32 + ni * 16 + lr) * 80 + lk * 16;
                bfh[ni] = *(const bf16x8*)((const char*)Bh + rb);
                bfl[ni] = *(const bf16x8*)((const char*)Bl + rb);
            }
#pragma unroll
            for (int mi = 0; mi < 4; mi++)
#pragma unroll
                for (int ni = 0; ni < 2; ni++) {
                    acc[mi][ni] = __builtin_amdgcn_mfma_f32_16x16x32_bf16(
                        afh[mi], bfh[ni], acc[mi][ni], 0, 0, 0);
                    acc[mi][ni] = __builtin_amdgcn_mfma_f32_16x16x32_bf16(
                        afh[mi], bfl[ni], acc[mi][ni], 0, 0, 0);
                    acc[mi][ni] = __builtin_amdgcn_mfma_f32_16x16x32_bf16(
                        afl[mi], bfh[ni], acc[mi][ni], 0, 0, 0);
                }
            __syncthreads();
        }
        float* zp = ws + O_ZPRE + (size_t)dir * 2048 * G4_;
        int crow = (lane >> 4) * 4;
#pragma unroll
        for (int ni = 0; ni < 2; ni++) {
            int n = n0 + wc * 32 + ni * 16 + lr;
            float bias = bsv[n];
#pragma unroll
            for (int mi = 0; mi < 4; mi++) {
                int mb = m0 + wr * 64 + mi * 16 + crow;
#pragma unroll
                for (int j = 0; j < 4; j++) {
                    float val2 = acc[mi][ni][j] + bias;
                    __hip_atomic_store((unsigned*)(zp + (size_t)(mb + j) * G4_ + n),
                                       __float_as_uint(val2),
                                       __ATOMIC_RELAXED, __HIP_MEMORY_SCOPE_AGENT);
                }
            }
        }
        __syncthreads();   // drains vmcnt: all block's agent stores complete
        if (tid == 0)
            __hip_atomic_fetch_add(&ztag[dir * 16 + mtile], 1,
                                   __ATOMIC_RELEASE, __HIP_MEMORY_SCOPE_AGENT);
    }
}

// ------------------------------------------------- GEMM2: P = hidden @ Wcat + bvec
__global__ __launch_bounds__(256) void k_gemm2(float* __restrict__ ws) {
    __shared__ float As[16][64];
    __shared__ float Bs[16][64];
    int m0 = blockIdx.y * 64;
    int n0 = blockIdx.x * 64;
    int tid = threadIdx.x;
    const float* Ap = ws + O_HIDDEN;
    const float* Bp = ws + O_WCAT;
    const float* bv = ws + O_BVEC;
    float acc[4][4] = {};
    int a_m = tid >> 2, a_k = (tid & 3) << 2;
    int b_k = tid >> 4, b_n = (tid & 15) << 2;
    int ty = tid >> 4, tx = tid & 15;
    const float* arow = Ap + (size_t)(m0 + a_m) * KC_;
    for (int k0 = 0; k0 < KC_; k0 += 16) {
        float4 av = *(const float4*)(arow + k0 + a_k);
        float4 bvv = *(const float4*)(Bp + (size_t)(k0 + b_k) * NCAT_ + n0 + b_n);
        As[a_k + 0][a_m] = av.x; As[a_k + 1][a_m] = av.y;
        As[a_k + 2][a_m] = av.z; As[a_k + 3][a_m] = av.w;
        *(float4*)&Bs[b_k][b_n] = bvv;
        __syncthreads();
#pragma unroll
        for (int kk = 0; kk < 16; kk++) {
            float4 a4 = *(const float4*)&As[kk][ty * 4];
            float4 b4 = *(const float4*)&Bs[kk][tx * 4];
            acc[0][0] = fmaf(a4.x, b4.x, acc[0][0]); acc[0][1] = fmaf(a4.x, b4.y, acc[0][1]);
            acc[0][2] = fmaf(a4.x, b4.z, acc[0][2]); acc[0][3] = fmaf(a4.x, b4.w, acc[0][3]);
            acc[1][0] = fmaf(a4.y, b4.x, acc[1][0]); acc[1][1] = fmaf(a4.y, b4.y, acc[1][1]);
            acc[1][2] = fmaf(a4.y, b4.z, acc[1][2]); acc[1][3] = fmaf(a4.y, b4.w, acc[1][3]);
            acc[2][0] = fmaf(a4.z, b4.x, acc[2][0]); acc[2][1] = fmaf(a4.z, b4.y, acc[2][1]);
            acc[2][2] = fmaf(a4.z, b4.z, acc[2][2]); acc[2][3] = fmaf(a4.z, b4.w, acc[2][3]);
            acc[3][0] = fmaf(a4.w, b4.x, acc[3][0]); acc[3][1] = fmaf(a4.w, b4.y, acc[3][1]);
            acc[3][2] = fmaf(a4.w, b4.z, acc[3][2]); acc[3][3] = fmaf(a4.w, b4.w, acc[3][3]);
        }
        __syncthreads();
    }
    float4 bias = *(const float4*)(bv + n0 + tx * 4);
    float* Pp = ws + O_P + (size_t)m0 * NCAT_;
#pragma unroll
    for (int i = 0; i < 4; i++) {
        float4 o;
        o.x = acc[i][0] + bias.x; o.y = acc[i][1] + bias.y;
        o.z = acc[i][2] + bias.z; o.w = acc[i][3] + bias.w;
        *(float4*)(Pp + (size_t)(ty * 4 + i) * NCAT_ + n0 + tx * 4) = o;
    }
}

// ------------------------------------------------- fused decoder (r5 form, proven fastest)
// block 0: event chains (16 waves), publishes self-tagged preds evtag[b][i] = ((i+1)<<8)|p.
// blocks 1..128: 16 argument chains each; tag reads amortized via a cached 64-slot
// window (ONE agent load per 64 steps per lane + shfl). Tag polls use s_sleep
// backoff on miss. Both chains prefetch their P rows 2 steps ahead.
__global__ __launch_bounds__(1024) void k_dec(const float* __restrict__ We,
                                              const float* __restrict__ Wa,
                                              float* __restrict__ ws, float* __restrict__ out) {
    const float* P = ws + O_P;
    int* evtag = (int*)(ws + O_EVTAG);   // [16][128]
    int lane = threadIdx.x & 63;
    if (blockIdx.x == 0) {
        int b = threadIdx.x >> 6;
        float Cg = 0.0f;
        unsigned long long gmask = 0ull;
        float pv = (lane < E_) ? P[(size_t)(0 * B_ + b) * NCAT_ + 72 + lane] : 0.0f;
        float p1 = (lane < E_) ? P[(size_t)(1 * B_ + b) * NCAT_ + 72 + lane] : 0.0f;
        for (int i = 0; i < L_; i++) {
            float p2 = 0.0f;
            if (i + 2 < L_ && lane < E_) p2 = P[(size_t)((i + 2) * B_ + b) * NCAT_ + 72 + lane];
            float v = (lane < E_) ? (pv + Cg) : -INFINITY;
            float mv = v;
            int mi = (lane < E_) ? lane : 0x7fffffff;
#pragma unroll
            for (int off = 32; off; off >>= 1) {
                float ov = __shfl_down(mv, off);
                int oi = __shfl_down(mi, off);
                if (ov > mv || (ov == mv && oi < mi)) { mv = ov; mi = oi; }
            }
            int p = __shfl(mi, 0);
            if (lane == 0)
                __hip_atomic_store(&evtag[b * L_ + i], ((i + 1) << 8) | p,
                                   __ATOMIC_RELAXED, __HIP_MEMORY_SCOPE_AGENT);
            if (lane < E_) out[(size_t)(b * L_ + i) * E_ + lane] = v;
            if (p > 0) {
                unsigned long long bit = 1ull << (p - 1);
                if (!(gmask & bit)) {
                    gmask |= bit;
                    if (lane < E_) Cg += We[lane * WES_ + 2 * H_ + (p - 1)];
                }
            }
            pv = p1; p1 = p2;
        }
    } else {
        int w = ((blockIdx.x - 1) << 4) + (threadIdx.x >> 6);  // 0..2047
        int b = w >> 7, j = w & 127;
        float* outa = out + (size_t)B_ * L_ * E_;
        float C = 0.0f;
        if (lane < A_) C = P[(size_t)(j * B_ + b) * NCAT_ + lane];
        unsigned long long ga = 0ull, gta = 0ull;
        float tv = (lane < A_) ? P[(size_t)(0 * B_ + b) * NCAT_ + 36 + lane] : 0.0f;
        float t1 = (lane < A_) ? P[(size_t)(1 * B_ + b) * NCAT_ + 36 + lane] : 0.0f;
        int myv = (int)0x80000000;   // cached tag word for window slot `lane`
        for (int i = 0; i < L_; i++) {
            float t2 = 0.0f;
            if (i + 2 < L_ && lane < A_) t2 = P[(size_t)((i + 2) * B_ + b) * NCAT_ + 36 + lane];
            int w0 = i & ~63;
            if ((i & 63) == 0)
                myv = __hip_atomic_load(&evtag[b * L_ + w0 + lane],
                                        __ATOMIC_RELAXED, __HIP_MEMORY_SCOPE_AGENT);
            int tv_tag = __shfl(myv, i & 63);
            if ((tv_tag >> 8) < i + 1) {   // wave-uniform miss: backoff poll
                int cnt = 0;
                do {
                    __builtin_amdgcn_s_sleep(1);
                    myv = __hip_atomic_load(&evtag[b * L_ + w0 + lane],
                                            __ATOMIC_RELAXED, __HIP_MEMORY_SCOPE_AGENT);
                    tv_tag = __shfl(myv, i & 63);
                } while ((tv_tag >> 8) < i + 1 && ++cnt < (1 << 18));
            }
            int ev = tv_tag & 0xff;
            float v = (lane < A_) ? (C + tv) : -INFINITY;
            float mv = v;
            int mi = (lane < A_) ? lane : 0x7fffffff;
#pragma unroll
            for (int off = 32; off; off >>= 1) {
                float ov = __shfl_down(mv, off);
                int oi = __shfl_down(mi, off);
                if (ov > mv || (ov == mv && oi < mi)) { mv = ov; mi = oi; }
            }
            int p = __shfl(mi, 0);
            if (lane < A_) outa[(size_t)((b * L_ + i) * L_ + j) * A_ + lane] = v;
            if (ev > 0 && p > 0) {
                unsigned long long bq = 1ull << (ev - 1);
                if (!(gta & bq)) {
                    gta |= bq;
                    if (lane < A_) C += Wa[lane * WAS_ + 4 * H_ + A_ - 1 + (ev - 1)];
                }
                unsigned long long br = 1ull << (p - 1);
                if (!(ga & br)) {
                    ga |= br;
                    if (lane < A_) C += Wa[lane * WAS_ + 4 * H_ + (p - 1)];
                }
            }
            tv = t1; t1 = t2;
        }
    }
}

// ----------------------------------------------------------------
extern "C" void kernel_launch(void* const* d_in, const int* in_sizes, int n_in,
                              void* d_out, int out_size, void* d_ws, size_t ws_size,
                              hipStream_t stream) {
    (void)in_sizes; (void)n_in; (void)out_size; (void)ws_size;
    const int*   ids   = (const int*)d_in[0];
    const float* emb   = (const float*)d_in[1];
    const float* Wih_f = (const float*)d_in[2];
    const float* Whh_f = (const float*)d_in[3];
    const float* bih_f = (const float*)d_in[4];
    const float* bhh_f = (const float*)d_in[5];
    const float* Wih_b = (const float*)d_in[6];
    const float* Whh_b = (const float*)d_in[7];
    const float* bih_b = (const float*)d_in[8];
    const float* bhh_b = (const float*)d_in[9];
    const float* We    = (const float*)d_in[10];
    const float* be    = (const float*)d_in[11];
    const float* Wa    = (const float*)d_in[12];
    const float* ba    = (const float*)d_in[13];
    float* out = (float*)d_out;
    float* ws  = (float*)d_ws;

    hipLaunchKernelGGL(k_prep, dim3(64), dim3(256), 0, stream,
                       bih_f, bhh_f, bih_b, bhh_b, We, be, Wa, ba, ws);
    hipLaunchKernelGGL(k_main, dim3(384), dim3(512), 0, stream,
                       ids, emb, Wih_f, Wih_b, Whh_f, Whh_b, ws);
    hipLaunchKernelGGL(k_gemm2, dim3(2, 32, 1), dim3(256), 0, stream, ws);
    hipLaunchKernelGGL(k_dec, dim3(129), dim3(1024), 0, stream, We, Wa, ws, out);
}

// Round 9
// 523.195 us; speedup vs baseline: 1.1005x; 1.1005x over previous
//
#include <hip/hip_runtime.h>
#include <math.h>

// Problem constants
#define B_  16
#define L_  128
#define E_  34
#define A_  36
#define D_  300
#define H_  256
#define KP_ 320     // D padded to mult of 32 (bf16 MFMA K)
#define G4_ 1024    // 4*H
#define KC_ 512     // 2*H
#define NCAT_ 128   // padded 36(base)+36(trig)+34(evh)
#define WAS_ 1092   // Wa row stride = 4H + A-1 + E-1
#define WES_ 545    // We row stride = 2H + E-1

// Workspace layout (float offsets)
#define O_XH     0u         // ushort[2048][320] X hi (bf16), rows m=t*16+b
#define O_XL     327680u    // ushort[2048][320] X lo
#define O_WH_F   655360u    // ushort[1024][320] Wih_f hi, ORIGINAL row-major
#define O_WH_B   819200u
#define O_WL_F   983040u
#define O_WL_B   1146880u
#define O_HX     1310720u   // u64[2][128][64] tagged h exchange (parity dbuf)
#define O_BSUM_F 1343488u   // [1024] bih+bhh
#define O_BSUM_B 1344512u
#define O_ZPRE   1345536u   // [2][128][16][1024]  x@WihT + bias, in processing order
#define O_HIDDEN 5539840u   // [128][16][512]  hs-layout (t,b), fwd [0:256), bwd [256:512)
#define O_WCAT   6588416u   // [512][128]  cols: 0..35 Wa_hidden, 36..71 Wa_trig, 72..105 We_hidden
#define O_BVEC   6653952u   // [128]       ba | 0 | be
#define O_P      6654080u   // [2048][128] hidden @ Wcat + bvec   (rows m = t*16+b)
#define O_EVTAG  6916224u   // int [16][128]  self-tagged event preds ((i+1)<<8 | p)

#define HIX(k) ((k) + (((k) >> 5) << 2))   // +4 float pad per 32 to stagger banks

// lgkm-only barrier: skips the vmcnt(0) store-ack/prefetch drain __syncthreads emits.
// Safe when the barrier only orders LDS traffic (global deps handled by data deps).
#define BARRIER_LGKM() asm volatile("s_waitcnt lgkmcnt(0)\n\ts_barrier" ::: "memory")

typedef short bf16x8 __attribute__((ext_vector_type(8)));
typedef float f32x4  __attribute__((ext_vector_type(4)));

__device__ __forceinline__ float fsig(float x) {
    return __builtin_amdgcn_rcpf(1.0f + __expf(-x));
}
__device__ __forceinline__ float ftanh(float x) {
    float e = __expf(-2.0f * fabsf(x));          // (0,1] - no overflow
    float t = (1.0f - e) * __builtin_amdgcn_rcpf(1.0f + e);
    return copysignf(t, x);
}
__device__ __forceinline__ unsigned short f2bf(float f) {   // RNE f32->bf16
    unsigned u = __float_as_uint(f);
    return (unsigned short)((u + 0x7fffu + ((u >> 16) & 1u)) >> 16);
}
__device__ __forceinline__ float bf2f(unsigned short h) {
    return __uint_as_float(((unsigned)h) << 16);
}

// ---------------------------------------------------------------- prep (+gather)
// Emits split-precision bf16 hi/lo pairs for X (gathered) and Wih (ORIGINAL
// [1024][320] row-major -- no transpose; the MFMA B-fragment wants 8 contiguous
// k per lane, which is exactly Wih row-major).
// hi = bf16(x); lo = bf16(x - hi). bf16 exponent range = fp32 -> no denormal loss.
// (r8 lesson: moving this staging into a fused producer-consumer kernel loses to
//  CU contention with the latency-bound LSTM -- keep it serial and cheap.)
__global__ void k_prep(const int* __restrict__ ids, const float* __restrict__ emb,
                       const float* __restrict__ Wih_f,
                       const float* __restrict__ bih_f, const float* __restrict__ bhh_f,
                       const float* __restrict__ Wih_b,
                       const float* __restrict__ bih_b, const float* __restrict__ bhh_b,
                       const float* __restrict__ We, const float* __restrict__ be,
                       const float* __restrict__ Wa, const float* __restrict__ ba,
                       float* __restrict__ ws) {
    const int N0 = 2048 * KP_;       // gathered embeddings (hi+lo written per elem)
    const int N1 = 2 * G4_ * KP_;    // Wih copies (hi+lo written per elem)
    const int N3 = 2 * 1024;         // bsum
    const int N4 = 65536;            // Wcat
    const int N5 = 128;              // bvec
    const int total = N0 + N1 + N3 + N4 + N5;
    unsigned short* xh = (unsigned short*)(ws + O_XH);
    unsigned short* xl = (unsigned short*)(ws + O_XL);
    for (int idx = blockIdx.x * blockDim.x + threadIdx.x; idx < total;
         idx += gridDim.x * blockDim.x) {
        int i = idx;
        if (i < N0) {
            int m = i / KP_, d = i - m * KP_;   // m = t*16+b
            int t = m >> 4, b = m & 15;
            int id = ids[b * L_ + t];
            float f = (d < D_) ? emb[(size_t)id * D_ + d] : 0.0f;
            unsigned short h = f2bf(f);
            xh[i] = h;
            xl[i] = f2bf(f - bf2f(h));
            continue;
        }
        i -= N0;
        if (i < N1) {
            int dir = i / (G4_ * KP_), rem = i % (G4_ * KP_);
            int r = rem / KP_, k = rem - r * KP_;
            const float* Wih = dir ? Wih_b : Wih_f;
            unsigned short* wh = (unsigned short*)(ws + (dir ? O_WH_B : O_WH_F));
            unsigned short* wl = (unsigned short*)(ws + (dir ? O_WL_B : O_WL_F));
            float f = (k < D_) ? Wih[r * D_ + k] : 0.0f;
            unsigned short h = f2bf(f);
            wh[rem] = h;
            wl[rem] = f2bf(f - bf2f(h));
            continue;
        }
        i -= N1;
        if (i < N3) {
            int dir = i / 1024, r = i % 1024;
            ws[(dir ? O_BSUM_B : O_BSUM_F) + r] =
                (dir ? bih_b[r] + bhh_b[r] : bih_f[r] + bhh_f[r]);
            continue;
        }
        i -= N3;
        if (i < N4) {
            int k = i >> 7, n = i & 127;
            float v = 0.0f;
            if (n < 36)               v = Wa[n * WAS_ + k];
            else if (n < 72)          v = Wa[(n - 36) * WAS_ + KC_ + k];
            else if (n < 106)         v = We[(n - 72) * WES_ + k];
            ws[O_WCAT + i] = v;
            continue;
        }
        i -= N4;
        {
            float v = 0.0f;
            if (i < 36)               v = ba[i];
            else if (i >= 72 && i < 106) v = be[i - 72];
            ws[O_BVEC + i] = v;
        }
    }
}

// ------------------------------------------------- GEMM1 (MFMA bf16x3): z = x @ WihT + bsum
// 128x128 tile, 4 waves (2x2 of 64x64), mfma_f32_16x16x32_bf16, K=320 in 10 steps.
// SPLIT PRECISION: z = Xh*Wh + Xh*Wl + Xl*Wh (lo*lo omitted, ~1e-7 RMS).
// fp32-equivalent accuracy at MFMA rates -- verified PASS at absmax 0.0039 (r5/r7).
__global__ __launch_bounds__(256) void k_gemm1(float* __restrict__ ws) {
    __shared__ unsigned short Ah[128][40];
    __shared__ unsigned short Al[128][40];
    __shared__ unsigned short Bh[128][40];
    __shared__ unsigned short Bl[128][40];
    int dir = blockIdx.z;
    int m0 = blockIdx.y * 128;
    int n0 = blockIdx.x * 128;
    int tid = threadIdx.x;
    const unsigned short* xh = (const unsigned short*)(ws + O_XH);
    const unsigned short* xl = (const unsigned short*)(ws + O_XL);
    const unsigned short* wh = (const unsigned short*)(ws + (dir ? O_WH_B : O_WH_F));
    const unsigned short* wl = (const unsigned short*)(ws + (dir ? O_WL_B : O_WL_F));
    const float* bsv = ws + (dir ? O_BSUM_B : O_BSUM_F);

    int w = tid >> 6, lane = tid & 63;
    int wr = w >> 1, wc = w & 1;
    int lr = lane & 15, lk = lane >> 4;

    int sr = tid >> 1, sh = tid & 1;
    int gm = m0 + sr;
    int tt = gm >> 4, bb2 = gm & 15;
    int srow = dir ? (((L_ - 1 - tt) << 4) | bb2) : gm;
    size_t aoff = (size_t)srow * KP_ + sh * 16;
    size_t boff = (size_t)(n0 + sr) * KP_ + sh * 16;
    int swb = sr * 80 + sh * 32;

    f32x4 acc[4][4] = {};
    for (int k0 = 0; k0 < KP_; k0 += 32) {
        float4 vah0 = *(const float4*)(xh + aoff + k0);
        float4 vah1 = *(const float4*)(xh + aoff + k0 + 8);
        float4 val0 = *(const float4*)(xl + aoff + k0);
        float4 val1 = *(const float4*)(xl + aoff + k0 + 8);
        float4 vbh0 = *(const float4*)(wh + boff + k0);
        float4 vbh1 = *(const float4*)(wh + boff + k0 + 8);
        float4 vbl0 = *(const float4*)(wl + boff + k0);
        float4 vbl1 = *(const float4*)(wl + boff + k0 + 8);
        *(float4*)((char*)&Ah[0][0] + swb) = vah0;
        *(float4*)((char*)&Ah[0][0] + swb + 16) = vah1;
        *(float4*)((char*)&Al[0][0] + swb) = val0;
        *(float4*)((char*)&Al[0][0] + swb + 16) = val1;
        *(float4*)((char*)&Bh[0][0] + swb) = vbh0;
        *(float4*)((char*)&Bh[0][0] + swb + 16) = vbh1;
        *(float4*)((char*)&Bl[0][0] + swb) = vbl0;
        *(float4*)((char*)&Bl[0][0] + swb + 16) = vbl1;
        __syncthreads();
        bf16x8 afh[4], afl[4], bfh[4], bfl[4];
#pragma unroll
        for (int mi = 0; mi < 4; mi++) {
            int rb = (wr * 64 + mi * 16 + lr) * 80 + lk * 16;
            afh[mi] = *(const bf16x8*)((const char*)&Ah[0][0] + rb);
            afl[mi] = *(const bf16x8*)((const char*)&Al[0][0] + rb);
        }
#pragma unroll
        for (int ni = 0; ni < 4; ni++) {
            int rb = (wc * 64 + ni * 16 + lr) * 80 + lk * 16;
            bfh[ni] = *(const bf16x8*)((const char*)&Bh[0][0] + rb);
            bfl[ni] = *(const bf16x8*)((const char*)&Bl[0][0] + rb);
        }
#pragma unroll
        for (int mi = 0; mi < 4; mi++)
#pragma unroll
            for (int ni = 0; ni < 4; ni++) {
                acc[mi][ni] = __builtin_amdgcn_mfma_f32_16x16x32_bf16(
                    afh[mi], bfh[ni], acc[mi][ni], 0, 0, 0);
                acc[mi][ni] = __builtin_amdgcn_mfma_f32_16x16x32_bf16(
                    afh[mi], bfl[ni], acc[mi][ni], 0, 0, 0);
                acc[mi][ni] = __builtin_amdgcn_mfma_f32_16x16x32_bf16(
                    afl[mi], bfh[ni], acc[mi][ni], 0, 0, 0);
            }
        __syncthreads();
    }
    float* zp = ws + O_ZPRE + (size_t)dir * 2048 * G4_;
    int crow = (lane >> 4) * 4;
#pragma unroll
    for (int ni = 0; ni < 4; ni++) {
        int n = n0 + wc * 64 + ni * 16 + lr;
        float bias = bsv[n];
#pragma unroll
        for (int mi = 0; mi < 4; mi++) {
            int mb = m0 + wr * 64 + mi * 16 + crow;
#pragma unroll
            for (int j = 0; j < 4; j++)
                zp[(size_t)(mb + j) * G4_ + n] = acc[mi][ni][j] + bias;
        }
    }
}

// ------------------------------------------------- LSTM: 128 blocks (r7 protocol
// + staggered poll train). phys = g*32 + (dir*16+b). Thread rg owns 4 consecutive
// gate rows of one gate; kc==0 writes z to zbuf; wave0 does activation + ONE
// coalesced 512B publish; waves 1-3 poll self-tagged u64s (relaxed agent atomics).
// (r1-r3: agent/MALL exchange is the floor. r8: fusing producers in regresses.)
// This revision: the consumer's retry quantum was a full serial MALL RTT (~900cy,
// loop-carried load). Replace with a 4-deep poll TRAIN: 4 independent relaxed
// loads of the same address issued ~64cy apart (s_sleep(1) stagger), checked
// oldest-first -- vmcnt waits only for the sample being checked, so discovery
// granularity drops to ~RTT/4. Same address, every sample tag-validated: pure
// issue-scheduling, no new coherence semantics.
__global__ __launch_bounds__(512, 2) void k_lstm(float* __restrict__ ws,
                                                 const float* __restrict__ Whh_f,
                                                 const float* __restrict__ Whh_b) {
    int phys = blockIdx.x;
    int g    = phys >> 5;
    int cb   = phys & 31;
    int b    = cb & 15;
    int dir  = cb >> 4;
    int tid  = threadIdx.x;
    int rg   = tid >> 3;             // 0..63 -> 4 local gate rows each
    int kc   = tid & 7;              // 0..7  -> k chunk of 32

    const float* Whh  = dir ? Whh_b : Whh_f;
    const float* zpre = ws + O_ZPRE + (size_t)dir * 2048 * G4_;
    float* hid = ws + O_HIDDEN;
    unsigned long long* hx64 = (unsigned long long*)(ws + O_HX);

    __shared__ float h_sh[HIX(255) + 1 + 4];
    __shared__ float zbuf[256];

    int lr0  = rg << 2;
    int ggr0 = (lr0 >> 6) * 256 + g * 64 + (lr0 & 63);
    float4 w[4][8];
#pragma unroll
    for (int i = 0; i < 4; i++) {
        const float* wr = Whh + (size_t)(ggr0 + i) * H_ + (kc << 5);
#pragma unroll
        for (int c = 0; c < 8; c++) w[i][c] = *(const float4*)(wr + (c << 2));
    }
    for (int k = tid; k < HIX(255) + 1 + 4; k += 512) h_sh[k] = 0.0f;
    float c_state = 0.0f;
    float4 zv = make_float4(0.f, 0.f, 0.f, 0.f);
    if (kc == 0) zv = *(const float4*)(zpre + (size_t)(0 * B_ + b) * G4_ + ggr0);
    __syncthreads();

    for (int s = 0; s < L_; s++) {
        float4 zn = make_float4(0.f, 0.f, 0.f, 0.f);
        if (kc == 0 && s + 1 < L_)
            zn = *(const float4*)(zpre + (size_t)((s + 1) * B_ + b) * G4_ + ggr0);
        float a0 = 0.f, a1 = 0.f, a2 = 0.f, a3 = 0.f;
        const float* hp = &h_sh[kc * 36];
#pragma unroll
        for (int c = 0; c < 8; c++) {
            float4 hv = *(const float4*)(hp + (c << 2));
            a0 = fmaf(w[0][c].x, hv.x, a0); a0 = fmaf(w[0][c].y, hv.y, a0);
            a0 = fmaf(w[0][c].z, hv.z, a0); a0 = fmaf(w[0][c].w, hv.w, a0);
            a1 = fmaf(w[1][c].x, hv.x, a1); a1 = fmaf(w[1][c].y, hv.y, a1);
            a1 = fmaf(w[1][c].z, hv.z, a1); a1 = fmaf(w[1][c].w, hv.w, a1);
            a2 = fmaf(w[2][c].x, hv.x, a2); a2 = fmaf(w[2][c].y, hv.y, a2);
            a2 = fmaf(w[2][c].z, hv.z, a2); a2 = fmaf(w[2][c].w, hv.w, a2);
            a3 = fmaf(w[3][c].x, hv.x, a3); a3 = fmaf(w[3][c].y, hv.y, a3);
            a3 = fmaf(w[3][c].w, hv.w, a3); a3 = fmaf(w[3][c].z, hv.z, a3);
        }
#pragma unroll
        for (int m = 1; m < 8; m <<= 1) {
            a0 += __shfl_xor(a0, m); a1 += __shfl_xor(a1, m);
            a2 += __shfl_xor(a2, m); a3 += __shfl_xor(a3, m);
        }
        if (kc == 0) {
            float4 z4;
            z4.x = a0 + zv.x; z4.y = a1 + zv.y; z4.z = a2 + zv.z; z4.w = a3 + zv.w;
            *(float4*)&zbuf[lr0] = z4;
        }
        zv = zn;
        BARRIER_LGKM();
        int par = (s + 1) & 1;
        if (tid < 64) {
            float fi = fsig(zbuf[tid]);
            float ff = fsig(zbuf[tid + 64]);
            float gg = ftanh(zbuf[tid + 128]);
            float fo = fsig(zbuf[tid + 192]);
            c_state = ff * c_state + fi * gg;
            float h = fo * ftanh(c_state);
            int hr = g * 64 + tid;
            // publish FIRST: visibility latency is the critical path
            if (s + 1 < L_) {
                unsigned long long pk =
                    ((unsigned long long)(unsigned)(s + 1) << 32) | (unsigned)__float_as_uint(h);
                __hip_atomic_store(&hx64[(par << 13) + (phys << 6) + tid], pk,
                                   __ATOMIC_RELAXED, __HIP_MEMORY_SCOPE_AGENT);
            }
            h_sh[HIX(hr)] = h;
            int t_orig = dir ? (L_ - 1 - s) : s;
            hid[(size_t)(t_orig * B_ + b) * KC_ + dir * H_ + hr] = h;
        }
        if (tid >= 64 && tid < 256 && s + 1 < L_) {
            int which = tid >> 6;                 // 1..3
            int sg = (g + which) & 3;
            int sb = cb | (sg << 5);              // sibling physical block id
            int u  = tid & 63;
            const unsigned long long* wp = &hx64[(par << 13) + (sb << 6) + u];
            unsigned long long v;
            // align first sample with publish visibility (~550cy post-barrier)
            __builtin_amdgcn_s_sleep(4);
            v = __hip_atomic_load(wp, __ATOMIC_RELAXED, __HIP_MEMORY_SCOPE_AGENT);
            int cnt = 0;
            while ((int)(v >> 32) < s + 1 && ++cnt < (1 << 18)) {
                // 4-deep staggered train: ~64cy sampling granularity
                unsigned long long w0 = __hip_atomic_load(wp, __ATOMIC_RELAXED,
                                                          __HIP_MEMORY_SCOPE_AGENT);
                __builtin_amdgcn_s_sleep(1);
                unsigned long long w1 = __hip_atomic_load(wp, __ATOMIC_RELAXED,
                                                          __HIP_MEMORY_SCOPE_AGENT);
                __builtin_amdgcn_s_sleep(1);
                unsigned long long w2 = __hip_atomic_load(wp, __ATOMIC_RELAXED,
                                                          __HIP_MEMORY_SCOPE_AGENT);
                __builtin_amdgcn_s_sleep(1);
                unsigned long long w3 = __hip_atomic_load(wp, __ATOMIC_RELAXED,
                                                          __HIP_MEMORY_SCOPE_AGENT);
                v = w0;
                if ((int)(v >> 32) < s + 1) v = w1;
                if ((int)(v >> 32) < s + 1) v = w2;
                if ((int)(v >> 32) < s + 1) v = w3;
            }
            h_sh[HIX(sg * 64 + u)] = __uint_as_float((unsigned)v);
        }
        BARRIER_LGKM();
    }
}

// ------------------------------------------------- GEMM2: P = hidden @ Wcat + bvec
__global__ __launch_bounds__(256) void k_gemm2(float* __restrict__ ws) {
    __shared__ float As[16][64];
    __shared__ float Bs[16][64];
    int m0 = blockIdx.y * 64;
    int n0 = blockIdx.x * 64;
    int tid = threadIdx.x;
    const float* Ap = ws + O_HIDDEN;
    const float* Bp = ws + O_WCAT;
    const float* bv = ws + O_BVEC;
    float acc[4][4] = {};
    int a_m = tid >> 2, a_k = (tid & 3) << 2;
    int b_k = tid >> 4, b_n = (tid & 15) << 2;
    int ty = tid >> 4, tx = tid & 15;
    const float* arow = Ap + (size_t)(m0 + a_m) * KC_;
    for (int k0 = 0; k0 < KC_; k0 += 16) {
        float4 av = *(const float4*)(arow + k0 + a_k);
        float4 bvv = *(const float4*)(Bp + (size_t)(k0 + b_k) * NCAT_ + n0 + b_n);
        As[a_k + 0][a_m] = av.x; As[a_k + 1][a_m] = av.y;
        As[a_k + 2][a_m] = av.z; As[a_k + 3][a_m] = av.w;
        *(float4*)&Bs[b_k][b_n] = bvv;
        __syncthreads();
#pragma unroll
        for (int kk = 0; kk < 16; kk++) {
            float4 a4 = *(const float4*)&As[kk][ty * 4];
            float4 b4 = *(const float4*)&Bs[kk][tx * 4];
            acc[0][0] = fmaf(a4.x, b4.x, acc[0][0]); acc[0][1] = fmaf(a4.x, b4.y, acc[0][1]);
            acc[0][2] = fmaf(a4.x, b4.z, acc[0][2]); acc[0][3] = fmaf(a4.x, b4.w, acc[0][3]);
            acc[1][0] = fmaf(a4.y, b4.x, acc[1][0]); acc[1][1] = fmaf(a4.y, b4.y, acc[1][1]);
            acc[1][2] = fmaf(a4.y, b4.z, acc[1][2]); acc[1][3] = fmaf(a4.y, b4.w, acc[1][3]);
            acc[2][0] = fmaf(a4.z, b4.x, acc[2][0]); acc[2][1] = fmaf(a4.z, b4.y, acc[2][1]);
            acc[2][2] = fmaf(a4.z, b4.z, acc[2][2]); acc[2][3] = fmaf(a4.z, b4.w, acc[2][3]);
            acc[3][0] = fmaf(a4.w, b4.x, acc[3][0]); acc[3][1] = fmaf(a4.w, b4.y, acc[3][1]);
            acc[3][2] = fmaf(a4.w, b4.z, acc[3][2]); acc[3][3] = fmaf(a4.w, b4.w, acc[3][3]);
        }
        __syncthreads();
    }
    float4 bias = *(const float4*)(bv + n0 + tx * 4);
    float* Pp = ws + O_P + (size_t)m0 * NCAT_;
#pragma unroll
    for (int i = 0; i < 4; i++) {
        float4 o;
        o.x = acc[i][0] + bias.x; o.y = acc[i][1] + bias.y;
        o.z = acc[i][2] + bias.z; o.w = acc[i][3] + bias.w;
        *(float4*)(Pp + (size_t)(ty * 4 + i) * NCAT_ + n0 + tx * 4) = o;
    }
}

// ------------------------------------------------- fused decoder (r5 form, proven fastest)
// block 0: event chains (16 waves), publishes self-tagged preds evtag[b][i] = ((i+1)<<8)|p.
// blocks 1..128: 16 argument chains each; tag reads amortized via a cached 64-slot
// window (ONE agent load per 64 steps per lane + shfl). Tag polls use s_sleep
// backoff on miss. Both chains prefetch their P rows 2 steps ahead.
__global__ __launch_bounds__(1024) void k_dec(const float* __restrict__ We,
                                              const float* __restrict__ Wa,
                                              float* __restrict__ ws, float* __restrict__ out) {
    const float* P = ws + O_P;
    int* evtag = (int*)(ws + O_EVTAG);   // [16][128]
    int lane = threadIdx.x & 63;
    if (blockIdx.x == 0) {
        int b = threadIdx.x >> 6;
        float Cg = 0.0f;
        unsigned long long gmask = 0ull;
        float pv = (lane < E_) ? P[(size_t)(0 * B_ + b) * NCAT_ + 72 + lane] : 0.0f;
        float p1 = (lane < E_) ? P[(size_t)(1 * B_ + b) * NCAT_ + 72 + lane] : 0.0f;
        for (int i = 0; i < L_; i++) {
            float p2 = 0.0f;
            if (i + 2 < L_ && lane < E_) p2 = P[(size_t)((i + 2) * B_ + b) * NCAT_ + 72 + lane];
            float v = (lane < E_) ? (pv + Cg) : -INFINITY;
            float mv = v;
            int mi = (lane < E_) ? lane : 0x7fffffff;
#pragma unroll
            for (int off = 32; off; off >>= 1) {
                float ov = __shfl_down(mv, off);
                int oi = __shfl_down(mi, off);
                if (ov > mv || (ov == mv && oi < mi)) { mv = ov; mi = oi; }
            }
            int p = __shfl(mi, 0);
            if (lane == 0)
                __hip_atomic_store(&evtag[b * L_ + i], ((i + 1) << 8) | p,
                                   __ATOMIC_RELAXED, __HIP_MEMORY_SCOPE_AGENT);
            if (lane < E_) out[(size_t)(b * L_ + i) * E_ + lane] = v;
            if (p > 0) {
                unsigned long long bit = 1ull << (p - 1);
                if (!(gmask & bit)) {
                    gmask |= bit;
                    if (lane < E_) Cg += We[lane * WES_ + 2 * H_ + (p - 1)];
                }
            }
            pv = p1; p1 = p2;
        }
    } else {
        int w = ((blockIdx.x - 1) << 4) + (threadIdx.x >> 6);  // 0..2047
        int b = w >> 7, j = w & 127;
        float* outa = out + (size_t)B_ * L_ * E_;
        float C = 0.0f;
        if (lane < A_) C = P[(size_t)(j * B_ + b) * NCAT_ + lane];
        unsigned long long ga = 0ull, gta = 0ull;
        float tv = (lane < A_) ? P[(size_t)(0 * B_ + b) * NCAT_ + 36 + lane] : 0.0f;
        float t1 = (lane < A_) ? P[(size_t)(1 * B_ + b) * NCAT_ + 36 + lane] : 0.0f;
        int myv = (int)0x80000000;   // cached tag word for window slot `lane`
        for (int i = 0; i < L_; i++) {
            float t2 = 0.0f;
            if (i + 2 < L_ && lane < A_) t2 = P[(size_t)((i + 2) * B_ + b) * NCAT_ + 36 + lane];
            int w0 = i & ~63;
            if ((i & 63) == 0)
                myv = __hip_atomic_load(&evtag[b * L_ + w0 + lane],
                                        __ATOMIC_RELAXED, __HIP_MEMORY_SCOPE_AGENT);
            int tv_tag = __shfl(myv, i & 63);
            if ((tv_tag >> 8) < i + 1) {   // wave-uniform miss: backoff poll
                int cnt = 0;
                do {
                    __builtin_amdgcn_s_sleep(1);
                    myv = __hip_atomic_load(&evtag[b * L_ + w0 + lane],
                                            __ATOMIC_RELAXED, __HIP_MEMORY_SCOPE_AGENT);
                    tv_tag = __shfl(myv, i & 63);
                } while ((tv_tag >> 8) < i + 1 && ++cnt < (1 << 18));
            }
            int ev = tv_tag & 0xff;
            float v = (lane < A_) ? (C + tv) : -INFINITY;
            float mv = v;
            int mi = (lane < A_) ? lane : 0x7fffffff;
#pragma unroll
            for (int off = 32; off; off >>= 1) {
                float ov = __shfl_down(mv, off);
                int oi = __shfl_down(mi, off);
                if (ov > mv || (ov == mv && oi < mi)) { mv = ov; mi = oi; }
            }
            int p = __shfl(mi, 0);
            if (lane < A_) outa[(size_t)((b * L_ + i) * L_ + j) * A_ + lane] = v;
            if (ev > 0 && p > 0) {
                unsigned long long bq = 1ull << (ev - 1);
                if (!(gta & bq)) {
                    gta |= bq;
                    if (lane < A_) C += Wa[lane * WAS_ + 4 * H_ + A_ - 1 + (ev - 1)];
                }
                unsigned long long br = 1ull << (p - 1);
                if (!(ga & br)) {
                    ga |= br;
                    if (lane < A_) C += Wa[lane * WAS_ + 4 * H_ + (p - 1)];
                }
            }
            tv = t1; t1 = t2;
        }
    }
}

// ----------------------------------------------------------------
extern "C" void kernel_launch(void* const* d_in, const int* in_sizes, int n_in,
                              void* d_out, int out_size, void* d_ws, size_t ws_size,
                              hipStream_t stream) {
    (void)in_sizes; (void)n_in; (void)out_size; (void)ws_size;
    const int*   ids   = (const int*)d_in[0];
    const float* emb   = (const float*)d_in[1];
    const float* Wih_f = (const float*)d_in[2];
    const float* Whh_f = (const float*)d_in[3];
    const float* bih_f = (const float*)d_in[4];
    const float* bhh_f = (const float*)d_in[5];
    const float* Wih_b = (const float*)d_in[6];
    const float* Whh_b = (const float*)d_in[7];
    const float* bih_b = (const float*)d_in[8];
    const float* bhh_b = (const float*)d_in[9];
    const float* We    = (const float*)d_in[10];
    const float* be    = (const float*)d_in[11];
    const float* Wa    = (const float*)d_in[12];
    const float* ba    = (const float*)d_in[13];
    float* out = (float*)d_out;
    float* ws  = (float*)d_ws;

    hipLaunchKernelGGL(k_prep, dim3(2048), dim3(256), 0, stream,
                       ids, emb, Wih_f, bih_f, bhh_f, Wih_b, bih_b, bhh_b,
                       We, be, Wa, ba, ws);
    hipLaunchKernelGGL(k_gemm1, dim3(8, 16, 2), dim3(256), 0, stream, ws);
    hipLaunchKernelGGL(k_lstm, dim3(128), dim3(512), 0, stream, ws, Whh_f, Whh_b);
    hipLaunchKernelGGL(k_gemm2, dim3(2, 32, 1), dim3(256), 0, stream, ws);
    hipLaunchKernelGGL(k_dec, dim3(129), dim3(1024), 0, stream, We, Wa, ws, out);
}

// Round 10
// 497.597 us; speedup vs baseline: 1.1571x; 1.0514x over previous
//
#include <hip/hip_runtime.h>
#include <math.h>

// Problem constants
#define B_  16
#define L_  128
#define E_  34
#define A_  36
#define D_  300
#define H_  256
#define KP_ 320     // D padded to mult of 32 (bf16 MFMA K)
#define G4_ 1024    // 4*H
#define KC_ 512     // 2*H
#define NCAT_ 128   // padded 36(base)+36(trig)+34(evh)
#define WAS_ 1092   // Wa row stride = 4H + A-1 + E-1
#define WES_ 545    // We row stride = 2H + E-1

// Workspace layout (float offsets)
#define O_XH     0u         // ushort[2048][320] X hi (bf16), rows m=t*16+b
#define O_XL     327680u    // ushort[2048][320] X lo
#define O_WH_F   655360u    // ushort[1024][320] Wih_f hi, ORIGINAL row-major
#define O_WH_B   819200u
#define O_WL_F   983040u
#define O_WL_B   1146880u
#define O_HX     1310720u   // u64[2][128][64] tagged h exchange (parity dbuf)
#define O_BSUM_F 1343488u   // [1024] bih+bhh
#define O_BSUM_B 1344512u
#define O_ZPRE   1345536u   // [2][128][16][1024]  x@WihT + bias, in processing order
#define O_HIDDEN 5539840u   // [128][16][512]  hs-layout (t,b), fwd [0:256), bwd [256:512)
#define O_WCAT   6588416u   // [512][128]  cols: 0..35 Wa_hidden, 36..71 Wa_trig, 72..105 We_hidden
#define O_BVEC   6653952u   // [128]       ba | 0 | be
#define O_P      6654080u   // [2048][128] hidden @ Wcat + bvec   (rows m = t*16+b)
#define O_EVTAG  6916224u   // int [16][128]  self-tagged event preds ((i+1)<<8 | p)

#define HIX(k) ((k) + (((k) >> 5) << 2))   // +4 float pad per 32 to stagger banks

// lgkm-only barrier: skips the vmcnt(0) store-ack/prefetch drain __syncthreads emits.
// Safe when the barrier only orders LDS traffic (global deps handled by data deps).
#define BARRIER_LGKM() asm volatile("s_waitcnt lgkmcnt(0)\n\ts_barrier" ::: "memory")

typedef short bf16x8 __attribute__((ext_vector_type(8)));
typedef float f32x4  __attribute__((ext_vector_type(4)));

__device__ __forceinline__ float fsig(float x) {
    return __builtin_amdgcn_rcpf(1.0f + __expf(-x));
}
__device__ __forceinline__ float ftanh(float x) {
    float e = __expf(-2.0f * fabsf(x));          // (0,1] - no overflow
    float t = (1.0f - e) * __builtin_amdgcn_rcpf(1.0f + e);
    return copysignf(t, x);
}
__device__ __forceinline__ unsigned short f2bf(float f) {   // RNE f32->bf16
    unsigned u = __float_as_uint(f);
    return (unsigned short)((u + 0x7fffu + ((u >> 16) & 1u)) >> 16);
}
__device__ __forceinline__ float bf2f(unsigned short h) {
    return __uint_as_float(((unsigned)h) << 16);
}

// ---------------------------------------------------------------- prep (+gather)
// Emits split-precision bf16 hi/lo pairs for X (gathered) and Wih (ORIGINAL
// [1024][320] row-major -- no transpose; the MFMA B-fragment wants 8 contiguous
// k per lane, which is exactly Wih row-major).
// hi = bf16(x); lo = bf16(x - hi). bf16 exponent range = fp32 -> no denormal loss.
// (r8 lesson: moving this staging into a fused producer-consumer kernel loses to
//  CU contention with the latency-bound LSTM -- keep it serial and cheap.)
__global__ void k_prep(const int* __restrict__ ids, const float* __restrict__ emb,
                       const float* __restrict__ Wih_f,
                       const float* __restrict__ bih_f, const float* __restrict__ bhh_f,
                       const float* __restrict__ Wih_b,
                       const float* __restrict__ bih_b, const float* __restrict__ bhh_b,
                       const float* __restrict__ We, const float* __restrict__ be,
                       const float* __restrict__ Wa, const float* __restrict__ ba,
                       float* __restrict__ ws) {
    const int N0 = 2048 * KP_;       // gathered embeddings (hi+lo written per elem)
    const int N1 = 2 * G4_ * KP_;    // Wih copies (hi+lo written per elem)
    const int N3 = 2 * 1024;         // bsum
    const int N4 = 65536;            // Wcat
    const int N5 = 128;              // bvec
    const int total = N0 + N1 + N3 + N4 + N5;
    unsigned short* xh = (unsigned short*)(ws + O_XH);
    unsigned short* xl = (unsigned short*)(ws + O_XL);
    for (int idx = blockIdx.x * blockDim.x + threadIdx.x; idx < total;
         idx += gridDim.x * blockDim.x) {
        int i = idx;
        if (i < N0) {
            int m = i / KP_, d = i - m * KP_;   // m = t*16+b
            int t = m >> 4, b = m & 15;
            int id = ids[b * L_ + t];
            float f = (d < D_) ? emb[(size_t)id * D_ + d] : 0.0f;
            unsigned short h = f2bf(f);
            xh[i] = h;
            xl[i] = f2bf(f - bf2f(h));
            continue;
        }
        i -= N0;
        if (i < N1) {
            int dir = i / (G4_ * KP_), rem = i % (G4_ * KP_);
            int r = rem / KP_, k = rem - r * KP_;
            const float* Wih = dir ? Wih_b : Wih_f;
            unsigned short* wh = (unsigned short*)(ws + (dir ? O_WH_B : O_WH_F));
            unsigned short* wl = (unsigned short*)(ws + (dir ? O_WL_B : O_WL_F));
            float f = (k < D_) ? Wih[r * D_ + k] : 0.0f;
            unsigned short h = f2bf(f);
            wh[rem] = h;
            wl[rem] = f2bf(f - bf2f(h));
            continue;
        }
        i -= N1;
        if (i < N3) {
            int dir = i / 1024, r = i % 1024;
            ws[(dir ? O_BSUM_B : O_BSUM_F) + r] =
                (dir ? bih_b[r] + bhh_b[r] : bih_f[r] + bhh_f[r]);
            continue;
        }
        i -= N3;
        if (i < N4) {
            int k = i >> 7, n = i & 127;
            float v = 0.0f;
            if (n < 36)               v = Wa[n * WAS_ + k];
            else if (n < 72)          v = Wa[(n - 36) * WAS_ + KC_ + k];
            else if (n < 106)         v = We[(n - 72) * WES_ + k];
            ws[O_WCAT + i] = v;
            continue;
        }
        i -= N4;
        {
            float v = 0.0f;
            if (i < 36)               v = ba[i];
            else if (i >= 72 && i < 106) v = be[i - 72];
            ws[O_BVEC + i] = v;
        }
    }
}

// ------------------------------------------------- GEMM1 (MFMA bf16x3): z = x @ WihT + bsum
// 128x128 tile, 4 waves (2x2 of 64x64), mfma_f32_16x16x32_bf16, K=320 in 10 steps.
// SPLIT PRECISION: z = Xh*Wh + Xh*Wl + Xl*Wh (lo*lo omitted, ~1e-7 RMS).
// fp32-equivalent accuracy at MFMA rates -- verified PASS at absmax 0.0039 (r5/r7).
__global__ __launch_bounds__(256) void k_gemm1(float* __restrict__ ws) {
    __shared__ unsigned short Ah[128][40];
    __shared__ unsigned short Al[128][40];
    __shared__ unsigned short Bh[128][40];
    __shared__ unsigned short Bl[128][40];
    int dir = blockIdx.z;
    int m0 = blockIdx.y * 128;
    int n0 = blockIdx.x * 128;
    int tid = threadIdx.x;
    const unsigned short* xh = (const unsigned short*)(ws + O_XH);
    const unsigned short* xl = (const unsigned short*)(ws + O_XL);
    const unsigned short* wh = (const unsigned short*)(ws + (dir ? O_WH_B : O_WH_F));
    const unsigned short* wl = (const unsigned short*)(ws + (dir ? O_WL_B : O_WL_F));
    const float* bsv = ws + (dir ? O_BSUM_B : O_BSUM_F);

    int w = tid >> 6, lane = tid & 63;
    int wr = w >> 1, wc = w & 1;
    int lr = lane & 15, lk = lane >> 4;

    int sr = tid >> 1, sh = tid & 1;
    int gm = m0 + sr;
    int tt = gm >> 4, bb2 = gm & 15;
    int srow = dir ? (((L_ - 1 - tt) << 4) | bb2) : gm;
    size_t aoff = (size_t)srow * KP_ + sh * 16;
    size_t boff = (size_t)(n0 + sr) * KP_ + sh * 16;
    int swb = sr * 80 + sh * 32;

    f32x4 acc[4][4] = {};
    for (int k0 = 0; k0 < KP_; k0 += 32) {
        float4 vah0 = *(const float4*)(xh + aoff + k0);
        float4 vah1 = *(const float4*)(xh + aoff + k0 + 8);
        float4 val0 = *(const float4*)(xl + aoff + k0);
        float4 val1 = *(const float4*)(xl + aoff + k0 + 8);
        float4 vbh0 = *(const float4*)(wh + boff + k0);
        float4 vbh1 = *(const float4*)(wh + boff + k0 + 8);
        float4 vbl0 = *(const float4*)(wl + boff + k0);
        float4 vbl1 = *(const float4*)(wl + boff + k0 + 8);
        *(float4*)((char*)&Ah[0][0] + swb) = vah0;
        *(float4*)((char*)&Ah[0][0] + swb + 16) = vah1;
        *(float4*)((char*)&Al[0][0] + swb) = val0;
        *(float4*)((char*)&Al[0][0] + swb + 16) = val1;
        *(float4*)((char*)&Bh[0][0] + swb) = vbh0;
        *(float4*)((char*)&Bh[0][0] + swb + 16) = vbh1;
        *(float4*)((char*)&Bl[0][0] + swb) = vbl0;
        *(float4*)((char*)&Bl[0][0] + swb + 16) = vbl1;
        __syncthreads();
        bf16x8 afh[4], afl[4], bfh[4], bfl[4];
#pragma unroll
        for (int mi = 0; mi < 4; mi++) {
            int rb = (wr * 64 + mi * 16 + lr) * 80 + lk * 16;
            afh[mi] = *(const bf16x8*)((const char*)&Ah[0][0] + rb);
            afl[mi] = *(const bf16x8*)((const char*)&Al[0][0] + rb);
        }
#pragma unroll
        for (int ni = 0; ni < 4; ni++) {
            int rb = (wc * 64 + ni * 16 + lr) * 80 + lk * 16;
            bfh[ni] = *(const bf16x8*)((const char*)&Bh[0][0] + rb);
            bfl[ni] = *(const bf16x8*)((const char*)&Bl[0][0] + rb);
        }
#pragma unroll
        for (int mi = 0; mi < 4; mi++)
#pragma unroll
            for (int ni = 0; ni < 4; ni++) {
                acc[mi][ni] = __builtin_amdgcn_mfma_f32_16x16x32_bf16(
                    afh[mi], bfh[ni], acc[mi][ni], 0, 0, 0);
                acc[mi][ni] = __builtin_amdgcn_mfma_f32_16x16x32_bf16(
                    afh[mi], bfl[ni], acc[mi][ni], 0, 0, 0);
                acc[mi][ni] = __builtin_amdgcn_mfma_f32_16x16x32_bf16(
                    afl[mi], bfh[ni], acc[mi][ni], 0, 0, 0);
            }
        __syncthreads();
    }
    float* zp = ws + O_ZPRE + (size_t)dir * 2048 * G4_;
    int crow = (lane >> 4) * 4;
#pragma unroll
    for (int ni = 0; ni < 4; ni++) {
        int n = n0 + wc * 64 + ni * 16 + lr;
        float bias = bsv[n];
#pragma unroll
        for (int mi = 0; mi < 4; mi++) {
            int mb = m0 + wr * 64 + mi * 16 + crow;
#pragma unroll
            for (int j = 0; j < 4; j++)
                zp[(size_t)(mb + j) * G4_ + n] = acc[mi][ni][j] + bias;
        }
    }
}

// ------------------------------------------------- LSTM: 128 blocks (r7 protocol, REVERTED)
// phys = g*32 + (dir*16+b). Thread rg owns 4 consecutive gate rows of one gate;
// kc==0 writes z to zbuf; wave0 does activation + ONE coalesced 512B publish;
// waves 1-3 poll self-tagged u64s (relaxed agent atomics).
// Protocol history: r1-r3 (L2 shortcuts) break or cost; r8 (fused producers)
// contends for CUs; r9 (4-deep poll train) forces vmcnt(0) over the whole train
// -> retry quantum grew. r7's form -- publish-first + s_sleep(6) phase alignment
// + simple poll -- measured 201us and is the protocol floor. Kept byte-exact.
__global__ __launch_bounds__(512, 2) void k_lstm(float* __restrict__ ws,
                                                 const float* __restrict__ Whh_f,
                                                 const float* __restrict__ Whh_b) {
    int phys = blockIdx.x;
    int g    = phys >> 5;
    int cb   = phys & 31;
    int b    = cb & 15;
    int dir  = cb >> 4;
    int tid  = threadIdx.x;
    int rg   = tid >> 3;             // 0..63 -> 4 local gate rows each
    int kc   = tid & 7;              // 0..7  -> k chunk of 32

    const float* Whh  = dir ? Whh_b : Whh_f;
    const float* zpre = ws + O_ZPRE + (size_t)dir * 2048 * G4_;
    float* hid = ws + O_HIDDEN;
    unsigned long long* hx64 = (unsigned long long*)(ws + O_HX);

    __shared__ float h_sh[HIX(255) + 1 + 4];
    __shared__ float zbuf[256];

    int lr0  = rg << 2;
    int ggr0 = (lr0 >> 6) * 256 + g * 64 + (lr0 & 63);
    float4 w[4][8];
#pragma unroll
    for (int i = 0; i < 4; i++) {
        const float* wr = Whh + (size_t)(ggr0 + i) * H_ + (kc << 5);
#pragma unroll
        for (int c = 0; c < 8; c++) w[i][c] = *(const float4*)(wr + (c << 2));
    }
    for (int k = tid; k < HIX(255) + 1 + 4; k += 512) h_sh[k] = 0.0f;
    float c_state = 0.0f;
    float4 zv = make_float4(0.f, 0.f, 0.f, 0.f);
    if (kc == 0) zv = *(const float4*)(zpre + (size_t)(0 * B_ + b) * G4_ + ggr0);
    __syncthreads();

    for (int s = 0; s < L_; s++) {
        float4 zn = make_float4(0.f, 0.f, 0.f, 0.f);
        if (kc == 0 && s + 1 < L_)
            zn = *(const float4*)(zpre + (size_t)((s + 1) * B_ + b) * G4_ + ggr0);
        float a0 = 0.f, a1 = 0.f, a2 = 0.f, a3 = 0.f;
        const float* hp = &h_sh[kc * 36];
#pragma unroll
        for (int c = 0; c < 8; c++) {
            float4 hv = *(const float4*)(hp + (c << 2));
            a0 = fmaf(w[0][c].x, hv.x, a0); a0 = fmaf(w[0][c].y, hv.y, a0);
            a0 = fmaf(w[0][c].z, hv.z, a0); a0 = fmaf(w[0][c].w, hv.w, a0);
            a1 = fmaf(w[1][c].x, hv.x, a1); a1 = fmaf(w[1][c].y, hv.y, a1);
            a1 = fmaf(w[1][c].z, hv.z, a1); a1 = fmaf(w[1][c].w, hv.w, a1);
            a2 = fmaf(w[2][c].x, hv.x, a2); a2 = fmaf(w[2][c].y, hv.y, a2);
            a2 = fmaf(w[2][c].z, hv.z, a2); a2 = fmaf(w[2][c].w, hv.w, a2);
            a3 = fmaf(w[3][c].x, hv.x, a3); a3 = fmaf(w[3][c].y, hv.y, a3);
            a3 = fmaf(w[3][c].z, hv.z, a3); a3 = fmaf(w[3][c].w, hv.w, a3);
        }
#pragma unroll
        for (int m = 1; m < 8; m <<= 1) {
            a0 += __shfl_xor(a0, m); a1 += __shfl_xor(a1, m);
            a2 += __shfl_xor(a2, m); a3 += __shfl_xor(a3, m);
        }
        if (kc == 0) {
            float4 z4;
            z4.x = a0 + zv.x; z4.y = a1 + zv.y; z4.z = a2 + zv.z; z4.w = a3 + zv.w;
            *(float4*)&zbuf[lr0] = z4;
        }
        zv = zn;
        BARRIER_LGKM();
        int par = (s + 1) & 1;
        if (tid < 64) {
            float fi = fsig(zbuf[tid]);
            float ff = fsig(zbuf[tid + 64]);
            float gg = ftanh(zbuf[tid + 128]);
            float fo = fsig(zbuf[tid + 192]);
            c_state = ff * c_state + fi * gg;
            float h = fo * ftanh(c_state);
            int hr = g * 64 + tid;
            // publish FIRST: visibility latency is the critical path
            if (s + 1 < L_) {
                unsigned long long pk =
                    ((unsigned long long)(unsigned)(s + 1) << 32) | (unsigned)__float_as_uint(h);
                __hip_atomic_store(&hx64[(par << 13) + (phys << 6) + tid], pk,
                                   __ATOMIC_RELAXED, __HIP_MEMORY_SCOPE_AGENT);
            }
            h_sh[HIX(hr)] = h;
            int t_orig = dir ? (L_ - 1 - s) : s;
            hid[(size_t)(t_orig * B_ + b) * KC_ + dir * H_ + hr] = h;
        }
        if (tid >= 64 && tid < 256 && s + 1 < L_) {
            int which = tid >> 6;                 // 1..3
            int sg = (g + which) & 3;
            int sb = cb | (sg << 5);              // sibling physical block id
            int u  = tid & 63;
            const unsigned long long* wp = &hx64[(par << 13) + (sb << 6) + u];
            unsigned long long v;
            int cnt = 0;
            // phase-align the first poll with publish visibility (~750cy post-barrier)
            __builtin_amdgcn_s_sleep(6);
            do {
                v = __hip_atomic_load(wp, __ATOMIC_RELAXED, __HIP_MEMORY_SCOPE_AGENT);
            } while ((int)(v >> 32) < s + 1 && ++cnt < (1 << 20));
            h_sh[HIX(sg * 64 + u)] = __uint_as_float((unsigned)v);
        }
        BARRIER_LGKM();
    }
}

// ------------------------------------------------- GEMM2: P = hidden @ Wcat + bvec
__global__ __launch_bounds__(256) void k_gemm2(float* __restrict__ ws) {
    __shared__ float As[16][64];
    __shared__ float Bs[16][64];
    int m0 = blockIdx.y * 64;
    int n0 = blockIdx.x * 64;
    int tid = threadIdx.x;
    const float* Ap = ws + O_HIDDEN;
    const float* Bp = ws + O_WCAT;
    const float* bv = ws + O_BVEC;
    float acc[4][4] = {};
    int a_m = tid >> 2, a_k = (tid & 3) << 2;
    int b_k = tid >> 4, b_n = (tid & 15) << 2;
    int ty = tid >> 4, tx = tid & 15;
    const float* arow = Ap + (size_t)(m0 + a_m) * KC_;
    for (int k0 = 0; k0 < KC_; k0 += 16) {
        float4 av = *(const float4*)(arow + k0 + a_k);
        float4 bvv = *(const float4*)(Bp + (size_t)(k0 + b_k) * NCAT_ + n0 + b_n);
        As[a_k + 0][a_m] = av.x; As[a_k + 1][a_m] = av.y;
        As[a_k + 2][a_m] = av.z; As[a_k + 3][a_m] = av.w;
        *(float4*)&Bs[b_k][b_n] = bvv;
        __syncthreads();
#pragma unroll
        for (int kk = 0; kk < 16; kk++) {
            float4 a4 = *(const float4*)&As[kk][ty * 4];
            float4 b4 = *(const float4*)&Bs[kk][tx * 4];
            acc[0][0] = fmaf(a4.x, b4.x, acc[0][0]); acc[0][1] = fmaf(a4.x, b4.y, acc[0][1]);
            acc[0][2] = fmaf(a4.x, b4.z, acc[0][2]); acc[0][3] = fmaf(a4.x, b4.w, acc[0][3]);
            acc[1][0] = fmaf(a4.y, b4.x, acc[1][0]); acc[1][1] = fmaf(a4.y, b4.y, acc[1][1]);
            acc[1][2] = fmaf(a4.y, b4.z, acc[1][2]); acc[1][3] = fmaf(a4.y, b4.w, acc[1][3]);
            acc[2][0] = fmaf(a4.z, b4.x, acc[2][0]); acc[2][1] = fmaf(a4.z, b4.y, acc[2][1]);
            acc[2][2] = fmaf(a4.z, b4.z, acc[2][2]); acc[2][3] = fmaf(a4.z, b4.w, acc[2][3]);
            acc[3][0] = fmaf(a4.w, b4.x, acc[3][0]); acc[3][1] = fmaf(a4.w, b4.y, acc[3][1]);
            acc[3][2] = fmaf(a4.w, b4.z, acc[3][2]); acc[3][3] = fmaf(a4.w, b4.w, acc[3][3]);
        }
        __syncthreads();
    }
    float4 bias = *(const float4*)(bv + n0 + tx * 4);
    float* Pp = ws + O_P + (size_t)m0 * NCAT_;
#pragma unroll
    for (int i = 0; i < 4; i++) {
        float4 o;
        o.x = acc[i][0] + bias.x; o.y = acc[i][1] + bias.y;
        o.z = acc[i][2] + bias.z; o.w = acc[i][3] + bias.w;
        *(float4*)(Pp + (size_t)(ty * 4 + i) * NCAT_ + n0 + tx * 4) = o;
    }
}

// ------------------------------------------------- fused decoder (r5 form + depth-3 ev prefetch)
// block 0: event chains (16 waves), publishes self-tagged preds evtag[b][i] = ((i+1)<<8)|p.
//   The ev chain is the decoder's serial rate limiter; its P-row prefetch is deepened
//   2 -> 3 steps (per-step work ~300-400cy vs IC RTT ~700-900cy: depth-2 was marginal).
// blocks 1..128: 16 argument chains each; tag reads amortized via a cached 64-slot
// window (ONE agent load per 64 steps per lane + shfl). Tag polls use s_sleep
// backoff on miss. Arg chains keep depth-2 (wave parallelism hides their latency).
__global__ __launch_bounds__(1024) void k_dec(const float* __restrict__ We,
                                              const float* __restrict__ Wa,
                                              float* __restrict__ ws, float* __restrict__ out) {
    const float* P = ws + O_P;
    int* evtag = (int*)(ws + O_EVTAG);   // [16][128]
    int lane = threadIdx.x & 63;
    if (blockIdx.x == 0) {
        int b = threadIdx.x >> 6;
        float Cg = 0.0f;
        unsigned long long gmask = 0ull;
        float pv = (lane < E_) ? P[(size_t)(0 * B_ + b) * NCAT_ + 72 + lane] : 0.0f;
        float p1 = (lane < E_) ? P[(size_t)(1 * B_ + b) * NCAT_ + 72 + lane] : 0.0f;
        float p2 = (lane < E_) ? P[(size_t)(2 * B_ + b) * NCAT_ + 72 + lane] : 0.0f;
        for (int i = 0; i < L_; i++) {
            float p3 = 0.0f;
            if (i + 3 < L_ && lane < E_) p3 = P[(size_t)((i + 3) * B_ + b) * NCAT_ + 72 + lane];
            float v = (lane < E_) ? (pv + Cg) : -INFINITY;
            float mv = v;
            int mi = (lane < E_) ? lane : 0x7fffffff;
#pragma unroll
            for (int off = 32; off; off >>= 1) {
                float ov = __shfl_down(mv, off);
                int oi = __shfl_down(mi, off);
                if (ov > mv || (ov == mv && oi < mi)) { mv = ov; mi = oi; }
            }
            int p = __shfl(mi, 0);
            if (lane == 0)
                __hip_atomic_store(&evtag[b * L_ + i], ((i + 1) << 8) | p,
                                   __ATOMIC_RELAXED, __HIP_MEMORY_SCOPE_AGENT);
            if (lane < E_) out[(size_t)(b * L_ + i) * E_ + lane] = v;
            if (p > 0) {
                unsigned long long bit = 1ull << (p - 1);
                if (!(gmask & bit)) {
                    gmask |= bit;
                    if (lane < E_) Cg += We[lane * WES_ + 2 * H_ + (p - 1)];
                }
            }
            pv = p1; p1 = p2; p2 = p3;
        }
    } else {
        int w = ((blockIdx.x - 1) << 4) + (threadIdx.x >> 6);  // 0..2047
        int b = w >> 7, j = w & 127;
        float* outa = out + (size_t)B_ * L_ * E_;
        float C = 0.0f;
        if (lane < A_) C = P[(size_t)(j * B_ + b) * NCAT_ + lane];
        unsigned long long ga = 0ull, gta = 0ull;
        float tv = (lane < A_) ? P[(size_t)(0 * B_ + b) * NCAT_ + 36 + lane] : 0.0f;
        float t1 = (lane < A_) ? P[(size_t)(1 * B_ + b) * NCAT_ + 36 + lane] : 0.0f;
        int myv = (int)0x80000000;   // cached tag word for window slot `lane`
        for (int i = 0; i < L_; i++) {
            float t2 = 0.0f;
            if (i + 2 < L_ && lane < A_) t2 = P[(size_t)((i + 2) * B_ + b) * NCAT_ + 36 + lane];
            int w0 = i & ~63;
            if ((i & 63) == 0)
                myv = __hip_atomic_load(&evtag[b * L_ + w0 + lane],
                                        __ATOMIC_RELAXED, __HIP_MEMORY_SCOPE_AGENT);
            int tv_tag = __shfl(myv, i & 63);
            if ((tv_tag >> 8) < i + 1) {   // wave-uniform miss: backoff poll
                int cnt = 0;
                do {
                    __builtin_amdgcn_s_sleep(1);
                    myv = __hip_atomic_load(&evtag[b * L_ + w0 + lane],
                                            __ATOMIC_RELAXED, __HIP_MEMORY_SCOPE_AGENT);
                    tv_tag = __shfl(myv, i & 63);
                } while ((tv_tag >> 8) < i + 1 && ++cnt < (1 << 18));
            }
            int ev = tv_tag & 0xff;
            float v = (lane < A_) ? (C + tv) : -INFINITY;
            float mv = v;
            int mi = (lane < A_) ? lane : 0x7fffffff;
#pragma unroll
            for (int off = 32; off; off >>= 1) {
                float ov = __shfl_down(mv, off);
                int oi = __shfl_down(mi, off);
                if (ov > mv || (ov == mv && oi < mi)) { mv = ov; mi = oi; }
            }
            int p = __shfl(mi, 0);
            if (lane < A_) outa[(size_t)((b * L_ + i) * L_ + j) * A_ + lane] = v;
            if (ev > 0 && p > 0) {
                unsigned long long bq = 1ull << (ev - 1);
                if (!(gta & bq)) {
                    gta |= bq;
                    if (lane < A_) C += Wa[lane * WAS_ + 4 * H_ + A_ - 1 + (ev - 1)];
                }
                unsigned long long br = 1ull << (p - 1);
                if (!(ga & br)) {
                    ga |= br;
                    if (lane < A_) C += Wa[lane * WAS_ + 4 * H_ + (p - 1)];
                }
            }
            tv = t1; t1 = t2;
        }
    }
}

// ----------------------------------------------------------------
extern "C" void kernel_launch(void* const* d_in, const int* in_sizes, int n_in,
                              void* d_out, int out_size, void* d_ws, size_t ws_size,
                              hipStream_t stream) {
    (void)in_sizes; (void)n_in; (void)out_size; (void)ws_size;
    const int*   ids   = (const int*)d_in[0];
    const float* emb   = (const float*)d_in[1];
    const float* Wih_f = (const float*)d_in[2];
    const float* Whh_f = (const float*)d_in[3];
    const float* bih_f = (const float*)d_in[4];
    const float* bhh_f = (const float*)d_in[5];
    const float* Wih_b = (const float*)d_in[6];
    const float* Whh_b = (const float*)d_in[7];
    const float* bih_b = (const float*)d_in[8];
    const float* bhh_b = (const float*)d_in[9];
    const float* We    = (const float*)d_in[10];
    const float* be    = (const float*)d_in[11];
    const float* Wa    = (const float*)d_in[12];
    const float* ba    = (const float*)d_in[13];
    float* out = (float*)d_out;
    float* ws  = (float*)d_ws;

    hipLaunchKernelGGL(k_prep, dim3(2048), dim3(256), 0, stream,
                       ids, emb, Wih_f, bih_f, bhh_f, Wih_b, bih_b, bhh_b,
                       We, be, Wa, ba, ws);
    hipLaunchKernelGGL(k_gemm1, dim3(8, 16, 2), dim3(256), 0, stream, ws);
    hipLaunchKernelGGL(k_lstm, dim3(128), dim3(512), 0, stream, ws, Whh_f, Whh_b);
    hipLaunchKernelGGL(k_gemm2, dim3(2, 32, 1), dim3(256), 0, stream, ws);
    hipLaunchKernelGGL(k_dec, dim3(129), dim3(1024), 0, stream, We, Wa, ws, out);
}

// Round 11
// 488.162 us; speedup vs baseline: 1.1795x; 1.0193x over previous
//
#include <hip/hip_runtime.h>
#include <math.h>

// Problem constants
#define B_  16
#define L_  128
#define E_  34
#define A_  36
#define D_  300
#define H_  256
#define KP_ 320     // D padded to mult of 32 (bf16 MFMA K)
#define G4_ 1024    // 4*H
#define KC_ 512     // 2*H
#define NCAT_ 128   // padded 36(base)+36(trig)+34(evh)
#define WAS_ 1092   // Wa row stride = 4H + A-1 + E-1
#define WES_ 545    // We row stride = 2H + E-1

// Workspace layout (float offsets)
#define O_HX     1310720u   // u64[2][128][64] tagged h exchange (parity dbuf)
#define O_BSUM_F 1343488u   // [1024] bih+bhh
#define O_BSUM_B 1344512u
#define O_ZPRE   1345536u   // [2][128][16][1024]  x@WihT + bias, in processing order
#define O_HIDDEN 5539840u   // [128][16][512]  hs-layout (t,b), fwd [0:256), bwd [256:512)
#define O_WCAT   6588416u   // [512][128]  cols: 0..35 Wa_hidden, 36..71 Wa_trig, 72..105 We_hidden
#define O_BVEC   6653952u   // [128]       ba | 0 | be
#define O_P      6654080u   // [2048][128] hidden @ Wcat + bvec   (rows m = t*16+b)
#define O_EVTAG  6916224u   // int [16][128]  self-tagged event preds ((i+1)<<8 | p)

#define HIX(k) ((k) + (((k) >> 5) << 2))   // +4 float pad per 32 to stagger banks

// lgkm-only barrier: skips the vmcnt(0) store-ack/prefetch drain __syncthreads emits.
// Safe when the barrier only orders LDS traffic (global deps handled by data deps).
#define BARRIER_LGKM() asm volatile("s_waitcnt lgkmcnt(0)\n\ts_barrier" ::: "memory")

typedef short bf16x8 __attribute__((ext_vector_type(8)));
typedef float f32x4  __attribute__((ext_vector_type(4)));

__device__ __forceinline__ float fsig(float x) {
    return __builtin_amdgcn_rcpf(1.0f + __expf(-x));
}
__device__ __forceinline__ float ftanh(float x) {
    float e = __expf(-2.0f * fabsf(x));          // (0,1] - no overflow
    float t = (1.0f - e) * __builtin_amdgcn_rcpf(1.0f + e);
    return copysignf(t, x);
}
__device__ __forceinline__ unsigned short f2bf(float f) {   // RNE f32->bf16
    unsigned u = __float_as_uint(f);
    return (unsigned short)((u + 0x7fffu + ((u >> 16) & 1u)) >> 16);
}
__device__ __forceinline__ float bf2f(unsigned short h) {
    return __uint_as_float(((unsigned)h) << 16);
}

// ---------------------------------------------------------------- prep (tiny)
// X/Wih hi-lo staging is gone: k_gemm1 now casts fp32->bf16 hi/lo IN-REGISTER
// while staging to LDS (r8 proved the cast path numerically; the r8 failure was
// CU co-residency with the LSTM, which does not apply to a standalone gemm1).
// Prep keeps only bsum / Wcat / bvec.
__global__ void k_prep(const float* __restrict__ bih_f, const float* __restrict__ bhh_f,
                       const float* __restrict__ bih_b, const float* __restrict__ bhh_b,
                       const float* __restrict__ We, const float* __restrict__ be,
                       const float* __restrict__ Wa, const float* __restrict__ ba,
                       float* __restrict__ ws) {
    const int N3 = 2 * 1024;     // bsum
    const int N4 = 65536;        // Wcat
    const int N5 = 128;          // bvec
    const int total = N3 + N4 + N5;
    for (int idx = blockIdx.x * blockDim.x + threadIdx.x; idx < total;
         idx += gridDim.x * blockDim.x) {
        int i = idx;
        if (i < N3) {
            int dir = i / 1024, r = i % 1024;
            ws[(dir ? O_BSUM_B : O_BSUM_F) + r] =
                (dir ? bih_b[r] + bhh_b[r] : bih_f[r] + bhh_f[r]);
            continue;
        }
        i -= N3;
        if (i < N4) {
            int k = i >> 7, n = i & 127;
            float v = 0.0f;
            if (n < 36)               v = Wa[n * WAS_ + k];
            else if (n < 72)          v = Wa[(n - 36) * WAS_ + KC_ + k];
            else if (n < 106)         v = We[(n - 72) * WES_ + k];
            ws[O_WCAT + i] = v;
            continue;
        }
        i -= N4;
        {
            float v = 0.0f;
            if (i < 36)               v = ba[i];
            else if (i >= 72 && i < 106) v = be[i - 72];
            ws[O_BVEC + i] = v;
        }
    }
}

// ------------------------------------------------- GEMM1 (MFMA bf16x3): z = x @ WihT + bsum
// 128x128 tile, 4 waves (2x2 of 64x64), mfma_f32_16x16x32_bf16, K=320 in 10 steps.
// SPLIT PRECISION: z = Xh*Wh + Xh*Wl + Xl*Wh (lo*lo omitted, ~1e-7 RMS) -- verified
// PASS at absmax 0.0039 (r5/r7/r10). This revision reads emb (ids-gathered) and
// Wih fp32 DIRECTLY and casts hi/lo in-register while staging (bitwise-identical
// values to the old prep-staged path; kills ~10MB of prep intermediate traffic).
__global__ __launch_bounds__(256) void k_gemm1(const int* __restrict__ ids,
                                               const float* __restrict__ emb,
                                               const float* __restrict__ Wih_f,
                                               const float* __restrict__ Wih_b,
                                               float* __restrict__ ws) {
    __shared__ unsigned short Ah[128][40];
    __shared__ unsigned short Al[128][40];
    __shared__ unsigned short Bh[128][40];
    __shared__ unsigned short Bl[128][40];
    int dir = blockIdx.z;
    int m0 = blockIdx.y * 128;
    int n0 = blockIdx.x * 128;
    int tid = threadIdx.x;
    const float* bsv = ws + (dir ? O_BSUM_B : O_BSUM_F);

    int w = tid >> 6, lane = tid & 63;
    int wr = w >> 1, wc = w & 1;
    int lr = lane & 15, lk = lane >> 4;

    // staging: thread t -> LDS row t>>1, 16 elems at half (t&1)
    int sr = tid >> 1, sh = tid & 1;
    int gm = m0 + sr;
    int tt = gm >> 4, bb2 = gm & 15;
    int t_orig = dir ? (L_ - 1 - tt) : tt;
    int aid = ids[bb2 * L_ + t_orig];
    const float* arow = emb + (size_t)aid * D_;
    const float* brow = (dir ? Wih_b : Wih_f) + (size_t)(n0 + sr) * D_;
    int swb = sr * 80 + sh * 32;

    f32x4 acc[4][4] = {};
    for (int k0 = 0; k0 < KP_; k0 += 32) {
        int c0 = k0 + sh * 16;
        float fa[16], fb[16];
        if (c0 + 16 <= D_) {
#pragma unroll
            for (int q = 0; q < 4; q++) {
                float4 va = *(const float4*)(arow + c0 + q * 4);
                float4 vb = *(const float4*)(brow + c0 + q * 4);
                fa[q * 4 + 0] = va.x; fa[q * 4 + 1] = va.y;
                fa[q * 4 + 2] = va.z; fa[q * 4 + 3] = va.w;
                fb[q * 4 + 0] = vb.x; fb[q * 4 + 1] = vb.y;
                fb[q * 4 + 2] = vb.z; fb[q * 4 + 3] = vb.w;
            }
        } else {
#pragma unroll
            for (int e = 0; e < 16; e++) {
                int c = c0 + e;
                fa[e] = (c < D_) ? arow[c] : 0.0f;
                fb[e] = (c < D_) ? brow[c] : 0.0f;
            }
        }
        bf16x8 ah0, ah1, al0, al1, bh0, bh1, bl0, bl1;
#pragma unroll
        for (int e = 0; e < 8; e++) {
            unsigned short h;
            h = f2bf(fa[e]);     ah0[e] = (short)h; al0[e] = (short)f2bf(fa[e] - bf2f(h));
            h = f2bf(fa[e + 8]); ah1[e] = (short)h; al1[e] = (short)f2bf(fa[e + 8] - bf2f(h));
            h = f2bf(fb[e]);     bh0[e] = (short)h; bl0[e] = (short)f2bf(fb[e] - bf2f(h));
            h = f2bf(fb[e + 8]); bh1[e] = (short)h; bl1[e] = (short)f2bf(fb[e + 8] - bf2f(h));
        }
        *(bf16x8*)((char*)&Ah[0][0] + swb) = ah0;
        *(bf16x8*)((char*)&Ah[0][0] + swb + 16) = ah1;
        *(bf16x8*)((char*)&Al[0][0] + swb) = al0;
        *(bf16x8*)((char*)&Al[0][0] + swb + 16) = al1;
        *(bf16x8*)((char*)&Bh[0][0] + swb) = bh0;
        *(bf16x8*)((char*)&Bh[0][0] + swb + 16) = bh1;
        *(bf16x8*)((char*)&Bl[0][0] + swb) = bl0;
        *(bf16x8*)((char*)&Bl[0][0] + swb + 16) = bl1;
        __syncthreads();
        bf16x8 afh[4], afl[4], bfh[4], bfl[4];
#pragma unroll
        for (int mi = 0; mi < 4; mi++) {
            int rb = (wr * 64 + mi * 16 + lr) * 80 + lk * 16;
            afh[mi] = *(const bf16x8*)((const char*)&Ah[0][0] + rb);
            afl[mi] = *(const bf16x8*)((const char*)&Al[0][0] + rb);
        }
#pragma unroll
        for (int ni = 0; ni < 4; ni++) {
            int rb = (wc * 64 + ni * 16 + lr) * 80 + lk * 16;
            bfh[ni] = *(const bf16x8*)((const char*)&Bh[0][0] + rb);
            bfl[ni] = *(const bf16x8*)((const char*)&Bl[0][0] + rb);
        }
#pragma unroll
        for (int mi = 0; mi < 4; mi++)
#pragma unroll
            for (int ni = 0; ni < 4; ni++) {
                acc[mi][ni] = __builtin_amdgcn_mfma_f32_16x16x32_bf16(
                    afh[mi], bfh[ni], acc[mi][ni], 0, 0, 0);
                acc[mi][ni] = __builtin_amdgcn_mfma_f32_16x16x32_bf16(
                    afh[mi], bfl[ni], acc[mi][ni], 0, 0, 0);
                acc[mi][ni] = __builtin_amdgcn_mfma_f32_16x16x32_bf16(
                    afl[mi], bfh[ni], acc[mi][ni], 0, 0, 0);
            }
        __syncthreads();
    }
    float* zp = ws + O_ZPRE + (size_t)dir * 2048 * G4_;
    int crow = (lane >> 4) * 4;
#pragma unroll
    for (int ni = 0; ni < 4; ni++) {
        int n = n0 + wc * 64 + ni * 16 + lr;
        float bias = bsv[n];
#pragma unroll
        for (int mi = 0; mi < 4; mi++) {
            int mb = m0 + wr * 64 + mi * 16 + crow;
#pragma unroll
            for (int j = 0; j < 4; j++)
                zp[(size_t)(mb + j) * G4_ + n] = acc[mi][ni][j] + bias;
        }
    }
}

// ------------------------------------------------- LSTM: 128 blocks (r7 protocol)
// phys = g*32 + (dir*16+b). Thread rg owns 4 consecutive gate rows of one gate;
// kc==0 writes z to zbuf; wave0 does activation + ONE coalesced 512B publish;
// waves 1-3 poll self-tagged u64s (relaxed agent atomics).
// Protocol history: r1-r3 (L2 shortcuts) break or cost; r8 (fused producers)
// contends for CUs; r9 (poll train) forces vmcnt(0) over the train. r7's form
// is the floor. THIS ROUND: s_sleep 6 -> 8 (first MALL read ~960cy post-act,
// closer to the ~750-900cy publish-visibility point; r7's 6 gave -12us but the
// measured step still carries ~1 retry on many steps).
__global__ __launch_bounds__(512, 2) void k_lstm(float* __restrict__ ws,
                                                 const float* __restrict__ Whh_f,
                                                 const float* __restrict__ Whh_b) {
    int phys = blockIdx.x;
    int g    = phys >> 5;
    int cb   = phys & 31;
    int b    = cb & 15;
    int dir  = cb >> 4;
    int tid  = threadIdx.x;
    int rg   = tid >> 3;             // 0..63 -> 4 local gate rows each
    int kc   = tid & 7;              // 0..7  -> k chunk of 32

    const float* Whh  = dir ? Whh_b : Whh_f;
    const float* zpre = ws + O_ZPRE + (size_t)dir * 2048 * G4_;
    float* hid = ws + O_HIDDEN;
    unsigned long long* hx64 = (unsigned long long*)(ws + O_HX);

    __shared__ float h_sh[HIX(255) + 1 + 4];
    __shared__ float zbuf[256];

    int lr0  = rg << 2;
    int ggr0 = (lr0 >> 6) * 256 + g * 64 + (lr0 & 63);
    float4 w[4][8];
#pragma unroll
    for (int i = 0; i < 4; i++) {
        const float* wr = Whh + (size_t)(ggr0 + i) * H_ + (kc << 5);
#pragma unroll
        for (int c = 0; c < 8; c++) w[i][c] = *(const float4*)(wr + (c << 2));
    }
    for (int k = tid; k < HIX(255) + 1 + 4; k += 512) h_sh[k] = 0.0f;
    float c_state = 0.0f;
    float4 zv = make_float4(0.f, 0.f, 0.f, 0.f);
    if (kc == 0) zv = *(const float4*)(zpre + (size_t)(0 * B_ + b) * G4_ + ggr0);
    __syncthreads();

    for (int s = 0; s < L_; s++) {
        float4 zn = make_float4(0.f, 0.f, 0.f, 0.f);
        if (kc == 0 && s + 1 < L_)
            zn = *(const float4*)(zpre + (size_t)((s + 1) * B_ + b) * G4_ + ggr0);
        float a0 = 0.f, a1 = 0.f, a2 = 0.f, a3 = 0.f;
        const float* hp = &h_sh[kc * 36];
#pragma unroll
        for (int c = 0; c < 8; c++) {
            float4 hv = *(const float4*)(hp + (c << 2));
            a0 = fmaf(w[0][c].x, hv.x, a0); a0 = fmaf(w[0][c].y, hv.y, a0);
            a0 = fmaf(w[0][c].z, hv.z, a0); a0 = fmaf(w[0][c].w, hv.w, a0);
            a1 = fmaf(w[1][c].x, hv.x, a1); a1 = fmaf(w[1][c].y, hv.y, a1);
            a1 = fmaf(w[1][c].z, hv.z, a1); a1 = fmaf(w[1][c].w, hv.w, a1);
            a2 = fmaf(w[2][c].x, hv.x, a2); a2 = fmaf(w[2][c].y, hv.y, a2);
            a2 = fmaf(w[2][c].z, hv.z, a2); a2 = fmaf(w[2][c].w, hv.w, a2);
            a3 = fmaf(w[3][c].x, hv.x, a3); a3 = fmaf(w[3][c].y, hv.y, a3);
            a3 = fmaf(w[3][c].z, hv.z, a3); a3 = fmaf(w[3][c].w, hv.w, a3);
        }
#pragma unroll
        for (int m = 1; m < 8; m <<= 1) {
            a0 += __shfl_xor(a0, m); a1 += __shfl_xor(a1, m);
            a2 += __shfl_xor(a2, m); a3 += __shfl_xor(a3, m);
        }
        if (kc == 0) {
            float4 z4;
            z4.x = a0 + zv.x; z4.y = a1 + zv.y; z4.z = a2 + zv.z; z4.w = a3 + zv.w;
            *(float4*)&zbuf[lr0] = z4;
        }
        zv = zn;
        BARRIER_LGKM();
        int par = (s + 1) & 1;
        if (tid < 64) {
            float fi = fsig(zbuf[tid]);
            float ff = fsig(zbuf[tid + 64]);
            float gg = ftanh(zbuf[tid + 128]);
            float fo = fsig(zbuf[tid + 192]);
            c_state = ff * c_state + fi * gg;
            float h = fo * ftanh(c_state);
            int hr = g * 64 + tid;
            // publish FIRST: visibility latency is the critical path
            if (s + 1 < L_) {
                unsigned long long pk =
                    ((unsigned long long)(unsigned)(s + 1) << 32) | (unsigned)__float_as_uint(h);
                __hip_atomic_store(&hx64[(par << 13) + (phys << 6) + tid], pk,
                                   __ATOMIC_RELAXED, __HIP_MEMORY_SCOPE_AGENT);
            }
            h_sh[HIX(hr)] = h;
            int t_orig = dir ? (L_ - 1 - s) : s;
            hid[(size_t)(t_orig * B_ + b) * KC_ + dir * H_ + hr] = h;
        }
        if (tid >= 64 && tid < 256 && s + 1 < L_) {
            int which = tid >> 6;                 // 1..3
            int sg = (g + which) & 3;
            int sb = cb | (sg << 5);              // sibling physical block id
            int u  = tid & 63;
            const unsigned long long* wp = &hx64[(par << 13) + (sb << 6) + u];
            unsigned long long v;
            int cnt = 0;
            // phase-align the first poll with publish visibility
            __builtin_amdgcn_s_sleep(8);
            do {
                v = __hip_atomic_load(wp, __ATOMIC_RELAXED, __HIP_MEMORY_SCOPE_AGENT);
            } while ((int)(v >> 32) < s + 1 && ++cnt < (1 << 20));
            h_sh[HIX(sg * 64 + u)] = __uint_as_float((unsigned)v);
        }
        BARRIER_LGKM();
    }
}

// ------------------------------------------------- GEMM2: P = hidden @ Wcat + bvec
__global__ __launch_bounds__(256) void k_gemm2(float* __restrict__ ws) {
    __shared__ float As[16][64];
    __shared__ float Bs[16][64];
    int m0 = blockIdx.y * 64;
    int n0 = blockIdx.x * 64;
    int tid = threadIdx.x;
    const float* Ap = ws + O_HIDDEN;
    const float* Bp = ws + O_WCAT;
    const float* bv = ws + O_BVEC;
    float acc[4][4] = {};
    int a_m = tid >> 2, a_k = (tid & 3) << 2;
    int b_k = tid >> 4, b_n = (tid & 15) << 2;
    int ty = tid >> 4, tx = tid & 15;
    const float* arow = Ap + (size_t)(m0 + a_m) * KC_;
    for (int k0 = 0; k0 < KC_; k0 += 16) {
        float4 av = *(const float4*)(arow + k0 + a_k);
        float4 bvv = *(const float4*)(Bp + (size_t)(k0 + b_k) * NCAT_ + n0 + b_n);
        As[a_k + 0][a_m] = av.x; As[a_k + 1][a_m] = av.y;
        As[a_k + 2][a_m] = av.z; As[a_k + 3][a_m] = av.w;
        *(float4*)&Bs[b_k][b_n] = bvv;
        __syncthreads();
#pragma unroll
        for (int kk = 0; kk < 16; kk++) {
            float4 a4 = *(const float4*)&As[kk][ty * 4];
            float4 b4 = *(const float4*)&Bs[kk][tx * 4];
            acc[0][0] = fmaf(a4.x, b4.x, acc[0][0]); acc[0][1] = fmaf(a4.x, b4.y, acc[0][1]);
            acc[0][2] = fmaf(a4.x, b4.z, acc[0][2]); acc[0][3] = fmaf(a4.x, b4.w, acc[0][3]);
            acc[1][0] = fmaf(a4.y, b4.x, acc[1][0]); acc[1][1] = fmaf(a4.y, b4.y, acc[1][1]);
            acc[1][2] = fmaf(a4.y, b4.z, acc[1][2]); acc[1][3] = fmaf(a4.y, b4.w, acc[1][3]);
            acc[2][0] = fmaf(a4.z, b4.x, acc[2][0]); acc[2][1] = fmaf(a4.z, b4.y, acc[2][1]);
            acc[2][2] = fmaf(a4.z, b4.z, acc[2][2]); acc[2][3] = fmaf(a4.z, b4.w, acc[2][3]);
            acc[3][0] = fmaf(a4.w, b4.x, acc[3][0]); acc[3][1] = fmaf(a4.w, b4.y, acc[3][1]);
            acc[3][2] = fmaf(a4.w, b4.z, acc[3][2]); acc[3][3] = fmaf(a4.w, b4.w, acc[3][3]);
        }
        __syncthreads();
    }
    float4 bias = *(const float4*)(bv + n0 + tx * 4);
    float* Pp = ws + O_P + (size_t)m0 * NCAT_;
#pragma unroll
    for (int i = 0; i < 4; i++) {
        float4 o;
        o.x = acc[i][0] + bias.x; o.y = acc[i][1] + bias.y;
        o.z = acc[i][2] + bias.z; o.w = acc[i][3] + bias.w;
        *(float4*)(Pp + (size_t)(ty * 4 + i) * NCAT_ + n0 + tx * 4) = o;
    }
}

// ------------------------------------------------- fused decoder (r10 form)
// block 0: event chains (16 waves), publishes self-tagged preds evtag[b][i] = ((i+1)<<8)|p;
//   depth-3 P-row prefetch (r10: -5us, the ev chain was mildly fetch-stalled).
// blocks 1..128: 16 argument chains each; tag reads amortized via a cached 64-slot
// window (ONE agent load per 64 steps per lane + shfl). Tag polls use s_sleep
// backoff on miss. Arg chains keep depth-2 (wave parallelism hides their latency).
__global__ __launch_bounds__(1024) void k_dec(const float* __restrict__ We,
                                              const float* __restrict__ Wa,
                                              float* __restrict__ ws, float* __restrict__ out) {
    const float* P = ws + O_P;
    int* evtag = (int*)(ws + O_EVTAG);   // [16][128]
    int lane = threadIdx.x & 63;
    if (blockIdx.x == 0) {
        int b = threadIdx.x >> 6;
        float Cg = 0.0f;
        unsigned long long gmask = 0ull;
        float pv = (lane < E_) ? P[(size_t)(0 * B_ + b) * NCAT_ + 72 + lane] : 0.0f;
        float p1 = (lane < E_) ? P[(size_t)(1 * B_ + b) * NCAT_ + 72 + lane] : 0.0f;
        float p2 = (lane < E_) ? P[(size_t)(2 * B_ + b) * NCAT_ + 72 + lane] : 0.0f;
        for (int i = 0; i < L_; i++) {
            float p3 = 0.0f;
            if (i + 3 < L_ && lane < E_) p3 = P[(size_t)((i + 3) * B_ + b) * NCAT_ + 72 + lane];
            float v = (lane < E_) ? (pv + Cg) : -INFINITY;
            float mv = v;
            int mi = (lane < E_) ? lane : 0x7fffffff;
#pragma unroll
            for (int off = 32; off; off >>= 1) {
                float ov = __shfl_down(mv, off);
                int oi = __shfl_down(mi, off);
                if (ov > mv || (ov == mv && oi < mi)) { mv = ov; mi = oi; }
            }
            int p = __shfl(mi, 0);
            if (lane == 0)
                __hip_atomic_store(&evtag[b * L_ + i], ((i + 1) << 8) | p,
                                   __ATOMIC_RELAXED, __HIP_MEMORY_SCOPE_AGENT);
            if (lane < E_) out[(size_t)(b * L_ + i) * E_ + lane] = v;
            if (p > 0) {
                unsigned long long bit = 1ull << (p - 1);
                if (!(gmask & bit)) {
                    gmask |= bit;
                    if (lane < E_) Cg += We[lane * WES_ + 2 * H_ + (p - 1)];
                }
            }
            pv = p1; p1 = p2; p2 = p3;
        }
    } else {
        int w = ((blockIdx.x - 1) << 4) + (threadIdx.x >> 6);  // 0..2047
        int b = w >> 7, j = w & 127;
        float* outa = out + (size_t)B_ * L_ * E_;
        float C = 0.0f;
        if (lane < A_) C = P[(size_t)(j * B_ + b) * NCAT_ + lane];
        unsigned long long ga = 0ull, gta = 0ull;
        float tv = (lane < A_) ? P[(size_t)(0 * B_ + b) * NCAT_ + 36 + lane] : 0.0f;
        float t1 = (lane < A_) ? P[(size_t)(1 * B_ + b) * NCAT_ + 36 + lane] : 0.0f;
        int myv = (int)0x80000000;   // cached tag word for window slot `lane`
        for (int i = 0; i < L_; i++) {
            float t2 = 0.0f;
            if (i + 2 < L_ && lane < A_) t2 = P[(size_t)((i + 2) * B_ + b) * NCAT_ + 36 + lane];
            int w0 = i & ~63;
            if ((i & 63) == 0)
                myv = __hip_atomic_load(&evtag[b * L_ + w0 + lane],
                                        __ATOMIC_RELAXED, __HIP_MEMORY_SCOPE_AGENT);
            int tv_tag = __shfl(myv, i & 63);
            if ((tv_tag >> 8) < i + 1) {   // wave-uniform miss: backoff poll
                int cnt = 0;
                do {
                    __builtin_amdgcn_s_sleep(1);
                    myv = __hip_atomic_load(&evtag[b * L_ + w0 + lane],
                                            __ATOMIC_RELAXED, __HIP_MEMORY_SCOPE_AGENT);
                    tv_tag = __shfl(myv, i & 63);
                } while ((tv_tag >> 8) < i + 1 && ++cnt < (1 << 18));
            }
            int ev = tv_tag & 0xff;
            float v = (lane < A_) ? (C + tv) : -INFINITY;
            float mv = v;
            int mi = (lane < A_) ? lane : 0x7fffffff;
#pragma unroll
            for (int off = 32; off; off >>= 1) {
                float ov = __shfl_down(mv, off);
                int oi = __shfl_down(mi, off);
                if (ov > mv || (ov == mv && oi < mi)) { mv = ov; mi = oi; }
            }
            int p = __shfl(mi, 0);
            if (lane < A_) outa[(size_t)((b * L_ + i) * L_ + j) * A_ + lane] = v;
            if (ev > 0 && p > 0) {
                unsigned long long bq = 1ull << (ev - 1);
                if (!(gta & bq)) {
                    gta |= bq;
                    if (lane < A_) C += Wa[lane * WAS_ + 4 * H_ + A_ - 1 + (ev - 1)];
                }
                unsigned long long br = 1ull << (p - 1);
                if (!(ga & br)) {
                    ga |= br;
                    if (lane < A_) C += Wa[lane * WAS_ + 4 * H_ + (p - 1)];
                }
            }
            tv = t1; t1 = t2;
        }
    }
}

// ----------------------------------------------------------------
extern "C" void kernel_launch(void* const* d_in, const int* in_sizes, int n_in,
                              void* d_out, int out_size, void* d_ws, size_t ws_size,
                              hipStream_t stream) {
    (void)in_sizes; (void)n_in; (void)out_size; (void)ws_size;
    const int*   ids   = (const int*)d_in[0];
    const float* emb   = (const float*)d_in[1];
    const float* Wih_f = (const float*)d_in[2];
    const float* Whh_f = (const float*)d_in[3];
    const float* bih_f = (const float*)d_in[4];
    const float* bhh_f = (const float*)d_in[5];
    const float* Wih_b = (const float*)d_in[6];
    const float* Whh_b = (const float*)d_in[7];
    const float* bih_b = (const float*)d_in[8];
    const float* bhh_b = (const float*)d_in[9];
    const float* We    = (const float*)d_in[10];
    const float* be    = (const float*)d_in[11];
    const float* Wa    = (const float*)d_in[12];
    const float* ba    = (const float*)d_in[13];
    float* out = (float*)d_out;
    float* ws  = (float*)d_ws;

    hipLaunchKernelGGL(k_prep, dim3(64), dim3(256), 0, stream,
                       bih_f, bhh_f, bih_b, bhh_b, We, be, Wa, ba, ws);
    hipLaunchKernelGGL(k_gemm1, dim3(8, 16, 2), dim3(256), 0, stream,
                       ids, emb, Wih_f, Wih_b, ws);
    hipLaunchKernelGGL(k_lstm, dim3(128), dim3(512), 0, stream, ws, Whh_f, Whh_b);
    hipLaunchKernelGGL(k_gemm2, dim3(2, 32, 1), dim3(256), 0, stream, ws);
    hipLaunchKernelGGL(k_dec, dim3(129), dim3(1024), 0, stream, We, Wa, ws, out);
}

// Round 12
// 484.250 us; speedup vs baseline: 1.1890x; 1.0081x over previous
//
#include <hip/hip_runtime.h>
#include <math.h>

// Problem constants
#define B_  16
#define L_  128
#define E_  34
#define A_  36
#define D_  300
#define H_  256
#define KP_ 320     // D padded to mult of 32 (bf16 MFMA K)
#define G4_ 1024    // 4*H
#define KC_ 512     // 2*H
#define NCAT_ 128   // padded 36(base)+36(trig)+34(evh)
#define WAS_ 1092   // Wa row stride = 4H + A-1 + E-1
#define WES_ 545    // We row stride = 2H + E-1

// Workspace layout (float offsets)
#define O_HX     1310720u   // u64[2][128][64] tagged h exchange (parity dbuf)
#define O_BSUM_F 1343488u   // [1024] bih+bhh
#define O_BSUM_B 1344512u
#define O_ZPRE   1345536u   // [2][128][16][1024]  x@WihT + bias, in processing order
#define O_HIDDEN 5539840u   // [128][16][512]  hs-layout (t,b), fwd [0:256), bwd [256:512)
#define O_WCAT   6588416u   // [512][128]  cols: 0..35 Wa_hidden, 36..71 Wa_trig, 72..105 We_hidden
#define O_BVEC   6653952u   // [128]       ba | 0 | be
#define O_P      6654080u   // [2048][128] hidden @ Wcat + bvec   (rows m = t*16+b)
#define O_EVTAG  6916224u   // int [16][128]  self-tagged event preds ((i+1)<<8 | p)

#define HIX(k) ((k) + (((k) >> 5) << 2))   // +4 float pad per 32 to stagger banks

// lgkm-only barrier: skips the vmcnt(0) store-ack/prefetch drain __syncthreads emits.
// Safe when the barrier only orders LDS traffic (global deps handled by data deps).
#define BARRIER_LGKM() asm volatile("s_waitcnt lgkmcnt(0)\n\ts_barrier" ::: "memory")

typedef short bf16x8 __attribute__((ext_vector_type(8)));
typedef float f32x4  __attribute__((ext_vector_type(4)));

__device__ __forceinline__ float fsig(float x) {
    return __builtin_amdgcn_rcpf(1.0f + __expf(-x));
}
__device__ __forceinline__ float ftanh(float x) {
    float e = __expf(-2.0f * fabsf(x));          // (0,1] - no overflow
    float t = (1.0f - e) * __builtin_amdgcn_rcpf(1.0f + e);
    return copysignf(t, x);
}
__device__ __forceinline__ unsigned short f2bf(float f) {   // RNE f32->bf16
    unsigned u = __float_as_uint(f);
    return (unsigned short)((u + 0x7fffu + ((u >> 16) & 1u)) >> 16);
}
__device__ __forceinline__ float bf2f(unsigned short h) {
    return __uint_as_float(((unsigned)h) << 16);
}

// ---------------------------------------------------------------- prep (tiny)
// X/Wih hi-lo staging is gone: k_gemm1 casts fp32->bf16 hi/lo IN-REGISTER while
// staging to LDS. Prep keeps only bsum / Wcat / bvec.
__global__ void k_prep(const float* __restrict__ bih_f, const float* __restrict__ bhh_f,
                       const float* __restrict__ bih_b, const float* __restrict__ bhh_b,
                       const float* __restrict__ We, const float* __restrict__ be,
                       const float* __restrict__ Wa, const float* __restrict__ ba,
                       float* __restrict__ ws) {
    const int N3 = 2 * 1024;     // bsum
    const int N4 = 65536;        // Wcat
    const int N5 = 128;          // bvec
    const int total = N3 + N4 + N5;
    for (int idx = blockIdx.x * blockDim.x + threadIdx.x; idx < total;
         idx += gridDim.x * blockDim.x) {
        int i = idx;
        if (i < N3) {
            int dir = i / 1024, r = i % 1024;
            ws[(dir ? O_BSUM_B : O_BSUM_F) + r] =
                (dir ? bih_b[r] + bhh_b[r] : bih_f[r] + bhh_f[r]);
            continue;
        }
        i -= N3;
        if (i < N4) {
            int k = i >> 7, n = i & 127;
            float v = 0.0f;
            if (n < 36)               v = Wa[n * WAS_ + k];
            else if (n < 72)          v = Wa[(n - 36) * WAS_ + KC_ + k];
            else if (n < 106)         v = We[(n - 72) * WES_ + k];
            ws[O_WCAT + i] = v;
            continue;
        }
        i -= N4;
        {
            float v = 0.0f;
            if (i < 36)               v = ba[i];
            else if (i >= 72 && i < 106) v = be[i - 72];
            ws[O_BVEC + i] = v;
        }
    }
}

// ------------------------------------------------- GEMM1 (MFMA bf16x3): z = x @ WihT + bsum
// 128x128 tile, 4 waves (2x2 of 64x64), mfma_f32_16x16x32_bf16, K=320 in 10 steps.
// SPLIT PRECISION: z = Xh*Wh + Xh*Wl + Xl*Wh (lo*lo omitted, ~1e-7 RMS) -- verified
// PASS at absmax 0.0039 (r5/r7/r10/r11). Reads emb (ids-gathered) and Wih fp32
// DIRECTLY, casting hi/lo in-register while staging.
__global__ __launch_bounds__(256) void k_gemm1(const int* __restrict__ ids,
                                               const float* __restrict__ emb,
                                               const float* __restrict__ Wih_f,
                                               const float* __restrict__ Wih_b,
                                               float* __restrict__ ws) {
    __shared__ unsigned short Ah[128][40];
    __shared__ unsigned short Al[128][40];
    __shared__ unsigned short Bh[128][40];
    __shared__ unsigned short Bl[128][40];
    int dir = blockIdx.z;
    int m0 = blockIdx.y * 128;
    int n0 = blockIdx.x * 128;
    int tid = threadIdx.x;
    const float* bsv = ws + (dir ? O_BSUM_B : O_BSUM_F);

    int w = tid >> 6, lane = tid & 63;
    int wr = w >> 1, wc = w & 1;
    int lr = lane & 15, lk = lane >> 4;

    // staging: thread t -> LDS row t>>1, 16 elems at half (t&1)
    int sr = tid >> 1, sh = tid & 1;
    int gm = m0 + sr;
    int tt = gm >> 4, bb2 = gm & 15;
    int t_orig = dir ? (L_ - 1 - tt) : tt;
    int aid = ids[bb2 * L_ + t_orig];
    const float* arow = emb + (size_t)aid * D_;
    const float* brow = (dir ? Wih_b : Wih_f) + (size_t)(n0 + sr) * D_;
    int swb = sr * 80 + sh * 32;

    f32x4 acc[4][4] = {};
    for (int k0 = 0; k0 < KP_; k0 += 32) {
        int c0 = k0 + sh * 16;
        float fa[16], fb[16];
        if (c0 + 16 <= D_) {
#pragma unroll
            for (int q = 0; q < 4; q++) {
                float4 va = *(const float4*)(arow + c0 + q * 4);
                float4 vb = *(const float4*)(brow + c0 + q * 4);
                fa[q * 4 + 0] = va.x; fa[q * 4 + 1] = va.y;
                fa[q * 4 + 2] = va.z; fa[q * 4 + 3] = va.w;
                fb[q * 4 + 0] = vb.x; fb[q * 4 + 1] = vb.y;
                fb[q * 4 + 2] = vb.z; fb[q * 4 + 3] = vb.w;
            }
        } else {
#pragma unroll
            for (int e = 0; e < 16; e++) {
                int c = c0 + e;
                fa[e] = (c < D_) ? arow[c] : 0.0f;
                fb[e] = (c < D_) ? brow[c] : 0.0f;
            }
        }
        bf16x8 ah0, ah1, al0, al1, bh0, bh1, bl0, bl1;
#pragma unroll
        for (int e = 0; e < 8; e++) {
            unsigned short h;
            h = f2bf(fa[e]);     ah0[e] = (short)h; al0[e] = (short)f2bf(fa[e] - bf2f(h));
            h = f2bf(fa[e + 8]); ah1[e] = (short)h; al1[e] = (short)f2bf(fa[e + 8] - bf2f(h));
            h = f2bf(fb[e]);     bh0[e] = (short)h; bl0[e] = (short)f2bf(fb[e] - bf2f(h));
            h = f2bf(fb[e + 8]); bh1[e] = (short)h; bl1[e] = (short)f2bf(fb[e + 8] - bf2f(h));
        }
        *(bf16x8*)((char*)&Ah[0][0] + swb) = ah0;
        *(bf16x8*)((char*)&Ah[0][0] + swb + 16) = ah1;
        *(bf16x8*)((char*)&Al[0][0] + swb) = al0;
        *(bf16x8*)((char*)&Al[0][0] + swb + 16) = al1;
        *(bf16x8*)((char*)&Bh[0][0] + swb) = bh0;
        *(bf16x8*)((char*)&Bh[0][0] + swb + 16) = bh1;
        *(bf16x8*)((char*)&Bl[0][0] + swb) = bl0;
        *(bf16x8*)((char*)&Bl[0][0] + swb + 16) = bl1;
        __syncthreads();
        bf16x8 afh[4], afl[4], bfh[4], bfl[4];
#pragma unroll
        for (int mi = 0; mi < 4; mi++) {
            int rb = (wr * 64 + mi * 16 + lr) * 80 + lk * 16;
            afh[mi] = *(const bf16x8*)((const char*)&Ah[0][0] + rb);
            afl[mi] = *(const bf16x8*)((const char*)&Al[0][0] + rb);
        }
#pragma unroll
        for (int ni = 0; ni < 4; ni++) {
            int rb = (wc * 64 + ni * 16 + lr) * 80 + lk * 16;
            bfh[ni] = *(const bf16x8*)((const char*)&Bh[0][0] + rb);
            bfl[ni] = *(const bf16x8*)((const char*)&Bl[0][0] + rb);
        }
#pragma unroll
        for (int mi = 0; mi < 4; mi++)
#pragma unroll
            for (int ni = 0; ni < 4; ni++) {
                acc[mi][ni] = __builtin_amdgcn_mfma_f32_16x16x32_bf16(
                    afh[mi], bfh[ni], acc[mi][ni], 0, 0, 0);
                acc[mi][ni] = __builtin_amdgcn_mfma_f32_16x16x32_bf16(
                    afh[mi], bfl[ni], acc[mi][ni], 0, 0, 0);
                acc[mi][ni] = __builtin_amdgcn_mfma_f32_16x16x32_bf16(
                    afl[mi], bfh[ni], acc[mi][ni], 0, 0, 0);
            }
        __syncthreads();
    }
    float* zp = ws + O_ZPRE + (size_t)dir * 2048 * G4_;
    int crow = (lane >> 4) * 4;
#pragma unroll
    for (int ni = 0; ni < 4; ni++) {
        int n = n0 + wc * 64 + ni * 16 + lr;
        float bias = bsv[n];
#pragma unroll
        for (int mi = 0; mi < 4; mi++) {
            int mb = m0 + wr * 64 + mi * 16 + crow;
#pragma unroll
            for (int j = 0; j < 4; j++)
                zp[(size_t)(mb + j) * G4_ + n] = acc[mi][ni][j] + bias;
        }
    }
}

// ------------------------------------------------- LSTM: 128 blocks (r7 protocol)
// phys = g*32 + (dir*16+b). Thread rg owns 4 consecutive gate rows of one gate;
// kc==0 writes z to zbuf; wave0 does activation + ONE coalesced 512B publish;
// waves 1-3 poll self-tagged u64s (relaxed agent atomics).
// Protocol history: r1-r3 (L2 shortcuts) break or cost; r8 (fused producers)
// contends for CUs; r9 (poll train) forces vmcnt(0) over the train.
// Sleep gradient: sleep(6)=201us (r7), sleep(8)=182us (r11; +128cy sleep bought
// -133cy/step -> misses still dominated). THIS ROUND: sleep(10)=640cy -- first
// poll arrives ~1090cy post-barrier, matching the implied ~900-1100cy publish
// visibility. Oversleep cost is bounded at 64cy/step per extra unit.
__global__ __launch_bounds__(512, 2) void k_lstm(float* __restrict__ ws,
                                                 const float* __restrict__ Whh_f,
                                                 const float* __restrict__ Whh_b) {
    int phys = blockIdx.x;
    int g    = phys >> 5;
    int cb   = phys & 31;
    int b    = cb & 15;
    int dir  = cb >> 4;
    int tid  = threadIdx.x;
    int rg   = tid >> 3;             // 0..63 -> 4 local gate rows each
    int kc   = tid & 7;              // 0..7  -> k chunk of 32

    const float* Whh  = dir ? Whh_b : Whh_f;
    const float* zpre = ws + O_ZPRE + (size_t)dir * 2048 * G4_;
    float* hid = ws + O_HIDDEN;
    unsigned long long* hx64 = (unsigned long long*)(ws + O_HX);

    __shared__ float h_sh[HIX(255) + 1 + 4];
    __shared__ float zbuf[256];

    int lr0  = rg << 2;
    int ggr0 = (lr0 >> 6) * 256 + g * 64 + (lr0 & 63);
    float4 w[4][8];
#pragma unroll
    for (int i = 0; i < 4; i++) {
        const float* wr = Whh + (size_t)(ggr0 + i) * H_ + (kc << 5);
#pragma unroll
        for (int c = 0; c < 8; c++) w[i][c] = *(const float4*)(wr + (c << 2));
    }
    for (int k = tid; k < HIX(255) + 1 + 4; k += 512) h_sh[k] = 0.0f;
    float c_state = 0.0f;
    float4 zv = make_float4(0.f, 0.f, 0.f, 0.f);
    if (kc == 0) zv = *(const float4*)(zpre + (size_t)(0 * B_ + b) * G4_ + ggr0);
    __syncthreads();

    for (int s = 0; s < L_; s++) {
        float4 zn = make_float4(0.f, 0.f, 0.f, 0.f);
        if (kc == 0 && s + 1 < L_)
            zn = *(const float4*)(zpre + (size_t)((s + 1) * B_ + b) * G4_ + ggr0);
        float a0 = 0.f, a1 = 0.f, a2 = 0.f, a3 = 0.f;
        const float* hp = &h_sh[kc * 36];
#pragma unroll
        for (int c = 0; c < 8; c++) {
            float4 hv = *(const float4*)(hp + (c << 2));
            a0 = fmaf(w[0][c].x, hv.x, a0); a0 = fmaf(w[0][c].y, hv.y, a0);
            a0 = fmaf(w[0][c].z, hv.z, a0); a0 = fmaf(w[0][c].w, hv.w, a0);
            a1 = fmaf(w[1][c].x, hv.x, a1); a1 = fmaf(w[1][c].y, hv.y, a1);
            a1 = fmaf(w[1][c].z, hv.z, a1); a1 = fmaf(w[1][c].w, hv.w, a1);
            a2 = fmaf(w[2][c].x, hv.x, a2); a2 = fmaf(w[2][c].y, hv.y, a2);
            a2 = fmaf(w[2][c].z, hv.z, a2); a2 = fmaf(w[2][c].w, hv.w, a2);
            a3 = fmaf(w[3][c].x, hv.x, a3); a3 = fmaf(w[3][c].y, hv.y, a3);
            a3 = fmaf(w[3][c].z, hv.z, a3); a3 = fmaf(w[3][c].w, hv.w, a3);
        }
#pragma unroll
        for (int m = 1; m < 8; m <<= 1) {
            a0 += __shfl_xor(a0, m); a1 += __shfl_xor(a1, m);
            a2 += __shfl_xor(a2, m); a3 += __shfl_xor(a3, m);
        }
        if (kc == 0) {
            float4 z4;
            z4.x = a0 + zv.x; z4.y = a1 + zv.y; z4.z = a2 + zv.z; z4.w = a3 + zv.w;
            *(float4*)&zbuf[lr0] = z4;
        }
        zv = zn;
        BARRIER_LGKM();
        int par = (s + 1) & 1;
        if (tid < 64) {
            float fi = fsig(zbuf[tid]);
            float ff = fsig(zbuf[tid + 64]);
            float gg = ftanh(zbuf[tid + 128]);
            float fo = fsig(zbuf[tid + 192]);
            c_state = ff * c_state + fi * gg;
            float h = fo * ftanh(c_state);
            int hr = g * 64 + tid;
            // publish FIRST: visibility latency is the critical path
            if (s + 1 < L_) {
                unsigned long long pk =
                    ((unsigned long long)(unsigned)(s + 1) << 32) | (unsigned)__float_as_uint(h);
                __hip_atomic_store(&hx64[(par << 13) + (phys << 6) + tid], pk,
                                   __ATOMIC_RELAXED, __HIP_MEMORY_SCOPE_AGENT);
            }
            h_sh[HIX(hr)] = h;
            int t_orig = dir ? (L_ - 1 - s) : s;
            hid[(size_t)(t_orig * B_ + b) * KC_ + dir * H_ + hr] = h;
        }
        if (tid >= 64 && tid < 256 && s + 1 < L_) {
            int which = tid >> 6;                 // 1..3
            int sg = (g + which) & 3;
            int sb = cb | (sg << 5);              // sibling physical block id
            int u  = tid & 63;
            const unsigned long long* wp = &hx64[(par << 13) + (sb << 6) + u];
            unsigned long long v;
            int cnt = 0;
            // phase-align the first poll with publish visibility
            __builtin_amdgcn_s_sleep(10);
            do {
                v = __hip_atomic_load(wp, __ATOMIC_RELAXED, __HIP_MEMORY_SCOPE_AGENT);
            } while ((int)(v >> 32) < s + 1 && ++cnt < (1 << 20));
            h_sh[HIX(sg * 64 + u)] = __uint_as_float((unsigned)v);
        }
        BARRIER_LGKM();
    }
}

// ------------------------------------------------- GEMM2: P = hidden @ Wcat + bvec
__global__ __launch_bounds__(256) void k_gemm2(float* __restrict__ ws) {
    __shared__ float As[16][64];
    __shared__ float Bs[16][64];
    int m0 = blockIdx.y * 64;
    int n0 = blockIdx.x * 64;
    int tid = threadIdx.x;
    const float* Ap = ws + O_HIDDEN;
    const float* Bp = ws + O_WCAT;
    const float* bv = ws + O_BVEC;
    float acc[4][4] = {};
    int a_m = tid >> 2, a_k = (tid & 3) << 2;
    int b_k = tid >> 4, b_n = (tid & 15) << 2;
    int ty = tid >> 4, tx = tid & 15;
    const float* arow = Ap + (size_t)(m0 + a_m) * KC_;
    for (int k0 = 0; k0 < KC_; k0 += 16) {
        float4 av = *(const float4*)(arow + k0 + a_k);
        float4 bvv = *(const float4*)(Bp + (size_t)(k0 + b_k) * NCAT_ + n0 + b_n);
        As[a_k + 0][a_m] = av.x; As[a_k + 1][a_m] = av.y;
        As[a_k + 2][a_m] = av.z; As[a_k + 3][a_m] = av.w;
        *(float4*)&Bs[b_k][b_n] = bvv;
        __syncthreads();
#pragma unroll
        for (int kk = 0; kk < 16; kk++) {
            float4 a4 = *(const float4*)&As[kk][ty * 4];
            float4 b4 = *(const float4*)&Bs[kk][tx * 4];
            acc[0][0] = fmaf(a4.x, b4.x, acc[0][0]); acc[0][1] = fmaf(a4.x, b4.y, acc[0][1]);
            acc[0][2] = fmaf(a4.x, b4.z, acc[0][2]); acc[0][3] = fmaf(a4.x, b4.w, acc[0][3]);
            acc[1][0] = fmaf(a4.y, b4.x, acc[1][0]); acc[1][1] = fmaf(a4.y, b4.y, acc[1][1]);
            acc[1][2] = fmaf(a4.y, b4.z, acc[1][2]); acc[1][3] = fmaf(a4.y, b4.w, acc[1][3]);
            acc[2][0] = fmaf(a4.z, b4.x, acc[2][0]); acc[2][1] = fmaf(a4.z, b4.y, acc[2][1]);
            acc[2][2] = fmaf(a4.z, b4.z, acc[2][2]); acc[2][3] = fmaf(a4.z, b4.w, acc[2][3]);
            acc[3][0] = fmaf(a4.w, b4.x, acc[3][0]); acc[3][1] = fmaf(a4.w, b4.y, acc[3][1]);
            acc[3][2] = fmaf(a4.w, b4.z, acc[3][2]); acc[3][3] = fmaf(a4.w, b4.w, acc[3][3]);
        }
        __syncthreads();
    }
    float4 bias = *(const float4*)(bv + n0 + tx * 4);
    float* Pp = ws + O_P + (size_t)m0 * NCAT_;
#pragma unroll
    for (int i = 0; i < 4; i++) {
        float4 o;
        o.x = acc[i][0] + bias.x; o.y = acc[i][1] + bias.y;
        o.z = acc[i][2] + bias.z; o.w = acc[i][3] + bias.w;
        *(float4*)(Pp + (size_t)(ty * 4 + i) * NCAT_ + n0 + tx * 4) = o;
    }
}

// ------------------------------------------------- fused decoder (r10 form)
// block 0: event chains (16 waves), publishes self-tagged preds evtag[b][i] = ((i+1)<<8)|p;
//   depth-3 P-row prefetch (r10: -5us, the ev chain was mildly fetch-stalled).
// blocks 1..128: 16 argument chains each; tag reads amortized via a cached 64-slot
// window (ONE agent load per 64 steps per lane + shfl). Tag polls use s_sleep
// backoff on miss. Arg chains keep depth-2 (wave parallelism hides their latency).
__global__ __launch_bounds__(1024) void k_dec(const float* __restrict__ We,
                                              const float* __restrict__ Wa,
                                              float* __restrict__ ws, float* __restrict__ out) {
    const float* P = ws + O_P;
    int* evtag = (int*)(ws + O_EVTAG);   // [16][128]
    int lane = threadIdx.x & 63;
    if (blockIdx.x == 0) {
        int b = threadIdx.x >> 6;
        float Cg = 0.0f;
        unsigned long long gmask = 0ull;
        float pv = (lane < E_) ? P[(size_t)(0 * B_ + b) * NCAT_ + 72 + lane] : 0.0f;
        float p1 = (lane < E_) ? P[(size_t)(1 * B_ + b) * NCAT_ + 72 + lane] : 0.0f;
        float p2 = (lane < E_) ? P[(size_t)(2 * B_ + b) * NCAT_ + 72 + lane] : 0.0f;
        for (int i = 0; i < L_; i++) {
            float p3 = 0.0f;
            if (i + 3 < L_ && lane < E_) p3 = P[(size_t)((i + 3) * B_ + b) * NCAT_ + 72 + lane];
            float v = (lane < E_) ? (pv + Cg) : -INFINITY;
            float mv = v;
            int mi = (lane < E_) ? lane : 0x7fffffff;
#pragma unroll
            for (int off = 32; off; off >>= 1) {
                float ov = __shfl_down(mv, off);
                int oi = __shfl_down(mi, off);
                if (ov > mv || (ov == mv && oi < mi)) { mv = ov; mi = oi; }
            }
            int p = __shfl(mi, 0);
            if (lane == 0)
                __hip_atomic_store(&evtag[b * L_ + i], ((i + 1) << 8) | p,
                                   __ATOMIC_RELAXED, __HIP_MEMORY_SCOPE_AGENT);
            if (lane < E_) out[(size_t)(b * L_ + i) * E_ + lane] = v;
            if (p > 0) {
                unsigned long long bit = 1ull << (p - 1);
                if (!(gmask & bit)) {
                    gmask |= bit;
                    if (lane < E_) Cg += We[lane * WES_ + 2 * H_ + (p - 1)];
                }
            }
            pv = p1; p1 = p2; p2 = p3;
        }
    } else {
        int w = ((blockIdx.x - 1) << 4) + (threadIdx.x >> 6);  // 0..2047
        int b = w >> 7, j = w & 127;
        float* outa = out + (size_t)B_ * L_ * E_;
        float C = 0.0f;
        if (lane < A_) C = P[(size_t)(j * B_ + b) * NCAT_ + lane];
        unsigned long long ga = 0ull, gta = 0ull;
        float tv = (lane < A_) ? P[(size_t)(0 * B_ + b) * NCAT_ + 36 + lane] : 0.0f;
        float t1 = (lane < A_) ? P[(size_t)(1 * B_ + b) * NCAT_ + 36 + lane] : 0.0f;
        int myv = (int)0x80000000;   // cached tag word for window slot `lane`
        for (int i = 0; i < L_; i++) {
            float t2 = 0.0f;
            if (i + 2 < L_ && lane < A_) t2 = P[(size_t)((i + 2) * B_ + b) * NCAT_ + 36 + lane];
            int w0 = i & ~63;
            if ((i & 63) == 0)
                myv = __hip_atomic_load(&evtag[b * L_ + w0 + lane],
                                        __ATOMIC_RELAXED, __HIP_MEMORY_SCOPE_AGENT);
            int tv_tag = __shfl(myv, i & 63);
            if ((tv_tag >> 8) < i + 1) {   // wave-uniform miss: backoff poll
                int cnt = 0;
                do {
                    __builtin_amdgcn_s_sleep(1);
                    myv = __hip_atomic_load(&evtag[b * L_ + w0 + lane],
                                            __ATOMIC_RELAXED, __HIP_MEMORY_SCOPE_AGENT);
                    tv_tag = __shfl(myv, i & 63);
                } while ((tv_tag >> 8) < i + 1 && ++cnt < (1 << 18));
            }
            int ev = tv_tag & 0xff;
            float v = (lane < A_) ? (C + tv) : -INFINITY;
            float mv = v;
            int mi = (lane < A_) ? lane : 0x7fffffff;
#pragma unroll
            for (int off = 32; off; off >>= 1) {
                float ov = __shfl_down(mv, off);
                int oi = __shfl_down(mi, off);
                if (ov > mv || (ov == mv && oi < mi)) { mv = ov; mi = oi; }
            }
            int p = __shfl(mi, 0);
            if (lane < A_) outa[(size_t)((b * L_ + i) * L_ + j) * A_ + lane] = v;
            if (ev > 0 && p > 0) {
                unsigned long long bq = 1ull << (ev - 1);
                if (!(gta & bq)) {
                    gta |= bq;
                    if (lane < A_) C += Wa[lane * WAS_ + 4 * H_ + A_ - 1 + (ev - 1)];
                }
                unsigned long long br = 1ull << (p - 1);
                if (!(ga & br)) {
                    ga |= br;
                    if (lane < A_) C += Wa[lane * WAS_ + 4 * H_ + (p - 1)];
                }
            }
            tv = t1; t1 = t2;
        }
    }
}

// ----------------------------------------------------------------
extern "C" void kernel_launch(void* const* d_in, const int* in_sizes, int n_in,
                              void* d_out, int out_size, void* d_ws, size_t ws_size,
                              hipStream_t stream) {
    (void)in_sizes; (void)n_in; (void)out_size; (void)ws_size;
    const int*   ids   = (const int*)d_in[0];
    const float* emb   = (const float*)d_in[1];
    const float* Wih_f = (const float*)d_in[2];
    const float* Whh_f = (const float*)d_in[3];
    const float* bih_f = (const float*)d_in[4];
    const float* bhh_f = (const float*)d_in[5];
    const float* Wih_b = (const float*)d_in[6];
    const float* Whh_b = (const float*)d_in[7];
    const float* bih_b = (const float*)d_in[8];
    const float* bhh_b = (const float*)d_in[9];
    const float* We    = (const float*)d_in[10];
    const float* be    = (const float*)d_in[11];
    const float* Wa    = (const float*)d_in[12];
    const float* ba    = (const float*)d_in[13];
    float* out = (float*)d_out;
    float* ws  = (float*)d_ws;

    hipLaunchKernelGGL(k_prep, dim3(64), dim3(256), 0, stream,
                       bih_f, bhh_f, bih_b, bhh_b, We, be, Wa, ba, ws);
    hipLaunchKernelGGL(k_gemm1, dim3(8, 16, 2), dim3(256), 0, stream,
                       ids, emb, Wih_f, Wih_b, ws);
    hipLaunchKernelGGL(k_lstm, dim3(128), dim3(512), 0, stream, ws, Whh_f, Whh_b);
    hipLaunchKernelGGL(k_gemm2, dim3(2, 32, 1), dim3(256), 0, stream, ws);
    hipLaunchKernelGGL(k_dec, dim3(129), dim3(1024), 0, stream, We, Wa, ws, out);
}